// Round 6
// baseline (368.261 us; speedup 1.0000x reference)
//
#include <hip/hip_runtime.h>
#include <hip/hip_bf16.h>
#include <stdint.h>

typedef unsigned short u16;
typedef short bf16x8 __attribute__((ext_vector_type(8)));
typedef float f32x4 __attribute__((ext_vector_type(4)));

#define DEV __device__ __forceinline__

DEV u16 f2bf(float f) {            // RNE (exact, for hi/lo splits)
  union { float f; uint32_t u; } v; v.f = f;
  uint32_t u = v.u;
  return (u16)((u + 0x7FFFu + ((u >> 16) & 1u)) >> 16);
}
DEV u16 f2bf_fast(float f) {       // round-half-up (cheap, for outputs)
  union { float f; uint32_t u; } v; v.f = f;
  return (u16)((v.u + 0x8000u) >> 16);
}
DEV float bf2f(u16 h) {
  union { uint32_t u; float f; } v; v.u = ((uint32_t)h) << 16;
  return v.f;
}
DEV uint32_t cvtpk_bf16(float lo, float hi) {   // dst[15:0]=bf(lo), dst[31:16]=bf(hi)
  uint32_t r;
  asm volatile("v_cvt_pk_bf16_f32 %0, %1, %2" : "=v"(r) : "v"(lo), "v"(hi));
  return r;
}

#if __has_builtin(__builtin_amdgcn_exp2f)
#define EXP2F(x) __builtin_amdgcn_exp2f(x)
#else
#define EXP2F(x) exp2f(x)
#endif

#define GLL(gp, lp) __builtin_amdgcn_global_load_lds(\
    (const __attribute__((address_space(1))) unsigned int*)(gp), \
    (__attribute__((address_space(3))) unsigned int*)(lp), 16, 0, 0)

// ---------------- prep kernels ----------------
__global__ void prep_x(const float* __restrict__ x, u16* __restrict__ xh, u16* __restrict__ xl) {
  int i = blockIdx.x * 256 + threadIdx.x;
  float4 v = ((const float4*)x)[i];
  ushort4 h, lo;
  h.x = f2bf(v.x); h.y = f2bf(v.y); h.z = f2bf(v.z); h.w = f2bf(v.w);
  lo.x = f2bf(v.x - bf2f(h.x)); lo.y = f2bf(v.y - bf2f(h.y));
  lo.z = f2bf(v.z - bf2f(h.z)); lo.w = f2bf(v.w - bf2f(h.w));
  ((ushort4*)xh)[i] = h;
  ((ushort4*)xl)[i] = lo;
}

__global__ void prep_w(const float* __restrict__ wq, const float* __restrict__ wk,
                       const float* __restrict__ wv, const float* __restrict__ wo,
                       u16* __restrict__ wqkh, u16* __restrict__ wqkl,
                       u16* __restrict__ wvb, u16* __restrict__ wob) {
  int i = blockIdx.x * 256 + threadIdx.x;
  int seg = i >> 18;
  int j = i & ((1 << 18) - 1);
  const float* src = (seg == 0) ? wq : (seg == 1) ? wk : (seg == 2) ? wv : wo;
  float4 v = ((const float4*)src)[j];
  ushort4 h;
  h.x = f2bf(v.x); h.y = f2bf(v.y); h.z = f2bf(v.z); h.w = f2bf(v.w);
  if (seg < 2) {
    ushort4 lo;
    lo.x = f2bf(v.x - bf2f(h.x)); lo.y = f2bf(v.y - bf2f(h.y));
    lo.z = f2bf(v.z - bf2f(h.z)); lo.w = f2bf(v.w - bf2f(h.w));
    ((ushort4*)wqkh)[i] = h;
    ((ushort4*)wqkl)[i] = lo;
  } else if (seg == 2) {
    ((ushort4*)wvb)[j] = h;
  } else {
    ((ushort4*)wob)[j] = h;
  }
}

// ---------------- fused QKV projection GEMM ----------------
__global__ __launch_bounds__(256, 2) void qkv_gemm(
    const u16* __restrict__ xh, const u16* __restrict__ xl,
    const u16* __restrict__ wh, const u16* __restrict__ wl,
    const u16* __restrict__ wv,
    u16* __restrict__ qkh, u16* __restrict__ qkl, u16* __restrict__ vout) {
  __shared__ u16 Ah[128 * 32], Al[128 * 32], Bh[128 * 32], Bl[128 * 32];
  const int t = threadIdx.x, w = t >> 6, l = t & 63, g = l >> 4, lr = l & 15;
  const int m0 = blockIdx.y * 128, n0 = blockIdx.x * 128;
  const bool split = (n0 < 2048);
  const u16* bsrc_h = split ? (wh + (size_t)n0 * 1024) : (wv + (size_t)(n0 - 2048) * 1024);
  const u16* bsrc_l = split ? (wl + (size_t)n0 * 1024) : wl;
  const int wr = w >> 1, wc = w & 1;

  f32x4 zero = {0.f, 0.f, 0.f, 0.f};
  f32x4 acc[4][4];
#pragma unroll
  for (int mi = 0; mi < 4; ++mi)
#pragma unroll
    for (int ni = 0; ni < 4; ++ni) acc[mi][ni] = zero;

  for (int k0 = 0; k0 < 1024; k0 += 32) {
    __syncthreads();
#pragma unroll
    for (int i = 0; i < 2; ++i) {
      const int c = i * 256 + t;
      const int row = c >> 2;
      const int kc8 = (c & 3) * 8;
      const size_t goff = (size_t)row * 1024 + k0 + kc8;
      const int lo = i * 4096 + w * 1024;
      GLL(xh + (size_t)m0 * 1024 + goff, (char*)Ah + lo);
      GLL(bsrc_h + goff, (char*)Bh + lo);
      if (split) {
        GLL(xl + (size_t)m0 * 1024 + goff, (char*)Al + lo);
        GLL(bsrc_l + goff, (char*)Bl + lo);
      }
    }
    __syncthreads();

    bf16x8 ah[4], al[4];
#pragma unroll
    for (int mi = 0; mi < 4; ++mi) {
      const int idx = (wr * 64 + mi * 16 + lr) * 32 + g * 8;
      ah[mi] = *(const bf16x8*)&Ah[idx];
      if (split) al[mi] = *(const bf16x8*)&Al[idx];
    }
#pragma unroll
    for (int ni = 0; ni < 4; ++ni) {
      const int idx = (wc * 64 + ni * 16 + lr) * 32 + g * 8;
      bf16x8 bh = *(const bf16x8*)&Bh[idx];
      bf16x8 bl;
      if (split) bl = *(const bf16x8*)&Bl[idx];
#pragma unroll
      for (int mi = 0; mi < 4; ++mi) {
        acc[mi][ni] = __builtin_amdgcn_mfma_f32_16x16x32_bf16(ah[mi], bh, acc[mi][ni], 0, 0, 0);
        if (split) {
          acc[mi][ni] = __builtin_amdgcn_mfma_f32_16x16x32_bf16(al[mi], bh, acc[mi][ni], 0, 0, 0);
          acc[mi][ni] = __builtin_amdgcn_mfma_f32_16x16x32_bf16(ah[mi], bl, acc[mi][ni], 0, 0, 0);
        }
      }
    }
  }

#pragma unroll
  for (int mi = 0; mi < 4; ++mi)
#pragma unroll
    for (int ni = 0; ni < 4; ++ni)
#pragma unroll
      for (int r = 0; r < 4; ++r) {
        const int row = m0 + wr * 64 + mi * 16 + g * 4 + r;
        const int col = wc * 64 + ni * 16 + lr;
        const float cval = acc[mi][ni][r];
        if (split) {
          const u16 h = f2bf(cval);
          qkh[(size_t)row * 2048 + n0 + col] = h;
          qkl[(size_t)row * 2048 + n0 + col] = f2bf(cval - bf2f(h));
        } else {
          vout[(size_t)row * 1024 + (n0 - 2048) + col] = f2bf(cval);
        }
      }
}

// ---------------- V transpose: vbf[8192][1024] -> vt[1024][8192] ----------------
__global__ __launch_bounds__(256) void vtrans(const u16* __restrict__ vin, u16* __restrict__ vout) {
  __shared__ u16 Ts[64 * 66];
  const int t = threadIdx.x;
  const int r0 = blockIdx.y * 64, c0 = blockIdx.x * 64;
  const int rl = t >> 3, cc = (t & 7) * 8;
#pragma unroll
  for (int i = 0; i < 2; ++i) {
    const int r = rl + i * 32;
    bf16x8 v = *(const bf16x8*)&vin[(size_t)(r0 + r) * 1024 + c0 + cc];
#pragma unroll
    for (int e = 0; e < 8; ++e) Ts[(cc + e) * 66 + r] = (u16)v[e];
  }
  __syncthreads();
  const int c = t >> 2, seg = (t & 3) * 16;
  u16 tmp[16];
#pragma unroll
  for (int e = 0; e < 16; ++e) tmp[e] = Ts[c * 66 + seg + e];
  *(bf16x8*)&vout[(size_t)(c0 + c) * 8192 + r0 + seg] = *(const bf16x8*)&tmp[0];
  *(bf16x8*)&vout[(size_t)(c0 + c) * 8192 + r0 + seg + 8] = *(const bf16x8*)&tmp[8];
}

// ---------------- flash attention with ALiBi (4 waves x 64q, 256 q/block) ----------------
// 64 q-rows/wave halves per-q K-tile LDS read cost (K reads amortized over 2x q).
// Swapped QK^T (lane-local softmax), dbuf K/V, 1 barrier/tile.
// VGPR peak ~215 -> launch_bounds(256,2): 2 waves/SIMD min -> cap 256.
__global__ __launch_bounds__(256, 2) void attn(
    const u16* __restrict__ qkh, const u16* __restrict__ qkl,
    const u16* __restrict__ vt, u16* __restrict__ multi) {
  __shared__ u16 Ksh[2][4096], Ksl[2][4096], Vts[2][4096];
  __shared__ u16 Ps[4][4096];
  const int t = threadIdx.x, w = t >> 6, l = t & 63, g = l >> 4, lr = l & 15;
  // XCD-chunked bijective swizzle
  const int L = blockIdx.x;
  const int flat = (L & 7) * 64 + (L >> 3);
  const int b = flat >> 7, h = (flat >> 3) & 15, qt = flat & 7;
  const int q0 = qt * 256;
  const size_t rowbase = (size_t)b * 2048;
  const u16* Qh = qkh + rowbase * 2048 + h * 64;
  const u16* Ql = qkl + rowbase * 2048 + h * 64;
  const u16* Kh = qkh + rowbase * 2048 + 1024 + h * 64;
  const u16* Kl = qkl + rowbase * 2048 + 1024 + h * 64;
  const u16* Vb = vt + (size_t)(h * 64) * 8192 + b * 2048;

  // staging: wave w stages rows w*16..w*16+15 of each 64x64 tile (2 GLLs per buffer)
  const int srow = l >> 3;
  const int sj = (l & 7) ^ srow;          // pre-swizzled source chunk (row&7 == srow for both halves)
  const int krow = w * 16 + srow;
  const int ldsoff = w * 2048;            // bytes
  u16* Pw = &Ps[w][0];                    // per-wave 64x64 P region

  bf16x8 qfh[4][2], qfl[4][2];
#pragma unroll
  for (int nt = 0; nt < 4; ++nt)
#pragma unroll
    for (int kc = 0; kc < 2; ++kc) {
      const size_t off = (size_t)(q0 + w * 64 + nt * 16 + lr) * 2048 + kc * 32 + g * 8;
      qfh[nt][kc] = *(const bf16x8*)&Qh[off];
      qfl[nt][kc] = *(const bf16x8*)&Ql[off];
    }

  f32x4 zero = {0.f, 0.f, 0.f, 0.f};
  f32x4 o[4][4];
#pragma unroll
  for (int mi = 0; mi < 4; ++mi)
#pragma unroll
    for (int dn = 0; dn < 4; ++dn) o[mi][dn] = zero;
  float mst[4] = {-3.0e38f, -3.0e38f, -3.0e38f, -3.0e38f};
  float lst[4] = {0.f, 0.f, 0.f, 0.f};

  // exp2-domain: v = s*c1 + slope2*k, k = kt + mt*16 + g*4 + r
  const float c1 = 0.125f * 1.44269504088896f;
  const float slope2 = -(float)(h + 1) * 1.44269504088896f;
  const float s2r1 = slope2, s2r2 = slope2 * 2.0f, s2r3 = slope2 * 3.0f;
  float base[4];
#pragma unroll
  for (int mt = 0; mt < 4; ++mt) base[mt] = slope2 * (float)(mt * 16 + g * 4);
  const float bstep = slope2 * 64.0f;
  const int sbase = (l & 48) | (g * 4);   // shfl source base for layout xfer

  // prologue: stage tile 0 into buffer 0
  GLL(Kh + (size_t)krow * 2048 + sj * 8, (char*)&Ksh[0][0] + ldsoff);
  GLL(Kh + (size_t)(krow + 8) * 2048 + sj * 8, (char*)&Ksh[0][0] + ldsoff + 1024);
  GLL(Kl + (size_t)krow * 2048 + sj * 8, (char*)&Ksl[0][0] + ldsoff);
  GLL(Kl + (size_t)(krow + 8) * 2048 + sj * 8, (char*)&Ksl[0][0] + ldsoff + 1024);
  GLL(Vb + (size_t)krow * 8192 + sj * 8, (char*)&Vts[0][0] + ldsoff);
  GLL(Vb + (size_t)(krow + 8) * 8192 + sj * 8, (char*)&Vts[0][0] + ldsoff + 1024);
  __syncthreads();

  int cur = 0;
  for (int kt = 0; kt < 2048; kt += 64) {
    if (kt + 64 < 2048) {
      const int nxt = cur ^ 1;
      const int kn = kt + 64;
      GLL(Kh + (size_t)(kn + krow) * 2048 + sj * 8, (char*)&Ksh[nxt][0] + ldsoff);
      GLL(Kh + (size_t)(kn + krow + 8) * 2048 + sj * 8, (char*)&Ksh[nxt][0] + ldsoff + 1024);
      GLL(Kl + (size_t)(kn + krow) * 2048 + sj * 8, (char*)&Ksl[nxt][0] + ldsoff);
      GLL(Kl + (size_t)(kn + krow + 8) * 2048 + sj * 8, (char*)&Ksl[nxt][0] + ldsoff + 1024);
      GLL(Vb + (size_t)krow * 8192 + kn + sj * 8, (char*)&Vts[nxt][0] + ldsoff);
      GLL(Vb + (size_t)(krow + 8) * 8192 + kn + sj * 8, (char*)&Vts[nxt][0] + ldsoff + 1024);
    }
    const u16* Kcur = &Ksh[cur][0];
    const u16* Lcur = &Ksl[cur][0];
    const u16* Vcur = &Vts[cur][0];

    // S^T = K x Q^T (3-product split bf16): c[mt][nt] rows=k, cols=q
    f32x4 c[4][4];
#pragma unroll
    for (int mt = 0; mt < 4; ++mt)
#pragma unroll
      for (int nt = 0; nt < 4; ++nt) c[mt][nt] = zero;
    __builtin_amdgcn_s_setprio(1);
#pragma unroll
    for (int mt = 0; mt < 4; ++mt) {
      bf16x8 ah[2], al[2];
#pragma unroll
      for (int kc = 0; kc < 2; ++kc) {
        const int rk = mt * 16 + lr;
        const int byte = rk * 128 + (((kc * 4 + g) ^ (rk & 7)) << 4);
        ah[kc] = *(const bf16x8*)((const char*)Kcur + byte);
        al[kc] = *(const bf16x8*)((const char*)Lcur + byte);
      }
#pragma unroll
      for (int nt = 0; nt < 4; ++nt) {
        f32x4 a = c[mt][nt];
        a = __builtin_amdgcn_mfma_f32_16x16x32_bf16(ah[0], qfh[nt][0], a, 0, 0, 0);
        a = __builtin_amdgcn_mfma_f32_16x16x32_bf16(ah[1], qfh[nt][1], a, 0, 0, 0);
        a = __builtin_amdgcn_mfma_f32_16x16x32_bf16(al[0], qfh[nt][0], a, 0, 0, 0);
        a = __builtin_amdgcn_mfma_f32_16x16x32_bf16(al[1], qfh[nt][1], a, 0, 0, 0);
        a = __builtin_amdgcn_mfma_f32_16x16x32_bf16(ah[0], qfl[nt][0], a, 0, 0, 0);
        a = __builtin_amdgcn_mfma_f32_16x16x32_bf16(ah[1], qfl[nt][1], a, 0, 0, 0);
        c[mt][nt] = a;
      }
    }
    __builtin_amdgcn_s_setprio(0);

    // ALiBi + lane-local online softmax
#pragma unroll
    for (int mt = 0; mt < 4; ++mt)
#pragma unroll
      for (int nt = 0; nt < 4; ++nt) {
        f32x4 a = c[mt][nt];
        a[0] = fmaf(a[0], c1, base[mt]);
        a[1] = fmaf(a[1], c1, base[mt] + s2r1);
        a[2] = fmaf(a[2], c1, base[mt] + s2r2);
        a[3] = fmaf(a[3], c1, base[mt] + s2r3);
        c[mt][nt] = a;
      }
    float rmax[4];
#pragma unroll
    for (int nt = 0; nt < 4; ++nt) {
      float m01 = fmaxf(fmaxf(c[0][nt][0], c[0][nt][1]), fmaxf(c[0][nt][2], c[0][nt][3]));
      float m23 = fmaxf(fmaxf(c[1][nt][0], c[1][nt][1]), fmaxf(c[1][nt][2], c[1][nt][3]));
      float m45 = fmaxf(fmaxf(c[2][nt][0], c[2][nt][1]), fmaxf(c[2][nt][2], c[2][nt][3]));
      float m67 = fmaxf(fmaxf(c[3][nt][0], c[3][nt][1]), fmaxf(c[3][nt][2], c[3][nt][3]));
      float m = fmaxf(fmaxf(m01, m23), fmaxf(m45, m67));
      m = fmaxf(m, __shfl_xor(m, 16));
      m = fmaxf(m, __shfl_xor(m, 32));
      rmax[nt] = m;
    }
    bool need = false;
#pragma unroll
    for (int nt = 0; nt < 4; ++nt) need |= (rmax[nt] > mst[nt]);
    if (__any(need)) {
      float alpha_sm[4];
#pragma unroll
      for (int nt = 0; nt < 4; ++nt) {
        const float mn = fmaxf(mst[nt], rmax[nt]);
        alpha_sm[nt] = EXP2F(mst[nt] - mn);
        mst[nt] = mn;
        lst[nt] *= alpha_sm[nt];
      }
#pragma unroll
      for (int mi = 0; mi < 4; ++mi)
#pragma unroll
        for (int r = 0; r < 4; ++r) {
          const float al_o = __shfl(alpha_sm[mi], sbase + r);
#pragma unroll
          for (int dn = 0; dn < 4; ++dn) o[mi][dn][r] *= al_o;
        }
    }
    // exp + packed P-write + row-sum
#pragma unroll
    for (int nt = 0; nt < 4; ++nt) {
      const int q = nt * 16 + lr;
      const int rowb = q * 128;
      const int qs = (q & 7);
      float rsum = 0.f;
#pragma unroll
      for (int mt = 0; mt < 4; ++mt) {
        const float p0 = EXP2F(c[mt][nt][0] - mst[nt]);
        const float p1 = EXP2F(c[mt][nt][1] - mst[nt]);
        const float p2 = EXP2F(c[mt][nt][2] - mst[nt]);
        const float p3 = EXP2F(c[mt][nt][3] - mst[nt]);
        rsum += (p0 + p1) + (p2 + p3);
        uint2 pk;
        pk.x = cvtpk_bf16(p0, p1);
        pk.y = cvtpk_bf16(p2, p3);
        const int c16 = 2 * mt + (g >> 1);
        const int byte = rowb + ((c16 ^ qs) << 4) + (g & 1) * 8;
        *(uint2*)((char*)Pw + byte) = pk;
      }
      rsum += __shfl_xor(rsum, 16);
      rsum += __shfl_xor(rsum, 32);
      lst[nt] += rsum;
    }

    // PV (reads P[q][k] swizzled layout)
    bf16x8 pa[4][2];
#pragma unroll
    for (int mi = 0; mi < 4; ++mi)
#pragma unroll
      for (int kc = 0; kc < 2; ++kc) {
        const int row = mi * 16 + lr;
        const int jk = kc * 4 + g;
        const int byte = row * 128 + ((jk ^ (row & 7)) << 4);
        pa[mi][kc] = *(const bf16x8*)((const char*)Pw + byte);
      }
    __builtin_amdgcn_s_setprio(1);
#pragma unroll
    for (int dn = 0; dn < 4; ++dn) {
      bf16x8 vb[2];
#pragma unroll
      for (int kc = 0; kc < 2; ++kc) {
        const int row = dn * 16 + lr;
        const int jk = kc * 4 + g;
        const int byte = row * 128 + ((jk ^ (row & 7)) << 4);
        vb[kc] = *(const bf16x8*)((const char*)Vcur + byte);
      }
#pragma unroll
      for (int mi = 0; mi < 4; ++mi) {
        o[mi][dn] = __builtin_amdgcn_mfma_f32_16x16x32_bf16(pa[mi][0], vb[0], o[mi][dn], 0, 0, 0);
        o[mi][dn] = __builtin_amdgcn_mfma_f32_16x16x32_bf16(pa[mi][1], vb[1], o[mi][dn], 0, 0, 0);
      }
    }
    __builtin_amdgcn_s_setprio(0);

#pragma unroll
    for (int mt = 0; mt < 4; ++mt) base[mt] += bstep;

    __syncthreads();   // vmcnt(0) drain: next tile's stage has landed
    cur ^= 1;
  }

  // epilogue: redistribute l from softmax layout to o layout, divide, store
#pragma unroll
  for (int mi = 0; mi < 4; ++mi)
#pragma unroll
    for (int r = 0; r < 4; ++r) {
      const float l_o = __shfl(lst[mi], sbase + r);
      const float rinv = 1.0f / l_o;
      const int qrow = q0 + w * 64 + mi * 16 + g * 4 + r;
#pragma unroll
      for (int dn = 0; dn < 4; ++dn) {
        const int d = dn * 16 + lr;
        multi[(rowbase + qrow) * 1024 + h * 64 + d] = f2bf_fast(o[mi][dn][r] * rinv);
      }
    }
}

// ---------------- output GEMM + bias ----------------
__global__ __launch_bounds__(256, 2) void out_gemm(
    const u16* __restrict__ A, const u16* __restrict__ Bw,
    const float* __restrict__ bias, float* __restrict__ out) {
  __shared__ u16 As[128 * 32], Bs[128 * 32];
  const int t = threadIdx.x, w = t >> 6, l = t & 63, g = l >> 4, lr = l & 15;
  const int m0 = blockIdx.y * 128, n0 = blockIdx.x * 128;
  const int wr = w >> 1, wc = w & 1;

  f32x4 zero = {0.f, 0.f, 0.f, 0.f};
  f32x4 acc[4][4];
#pragma unroll
  for (int mi = 0; mi < 4; ++mi)
#pragma unroll
    for (int ni = 0; ni < 4; ++ni) acc[mi][ni] = zero;

  for (int k0 = 0; k0 < 1024; k0 += 32) {
    __syncthreads();
#pragma unroll
    for (int i = 0; i < 2; ++i) {
      const int c = i * 256 + t;
      const int row = c >> 2;
      const int kc8 = (c & 3) * 8;
      const size_t goff = (size_t)row * 1024 + k0 + kc8;
      const int lo = i * 4096 + w * 1024;
      GLL(A + (size_t)m0 * 1024 + goff, (char*)As + lo);
      GLL(Bw + (size_t)n0 * 1024 + goff, (char*)Bs + lo);
    }
    __syncthreads();

    bf16x8 ah[4];
#pragma unroll
    for (int mi = 0; mi < 4; ++mi)
      ah[mi] = *(const bf16x8*)&As[(wr * 64 + mi * 16 + lr) * 32 + g * 8];
#pragma unroll
    for (int ni = 0; ni < 4; ++ni) {
      bf16x8 bh = *(const bf16x8*)&Bs[(wc * 64 + ni * 16 + lr) * 32 + g * 8];
#pragma unroll
      for (int mi = 0; mi < 4; ++mi)
        acc[mi][ni] = __builtin_amdgcn_mfma_f32_16x16x32_bf16(ah[mi], bh, acc[mi][ni], 0, 0, 0);
    }
  }

#pragma unroll
  for (int mi = 0; mi < 4; ++mi)
#pragma unroll
    for (int ni = 0; ni < 4; ++ni)
#pragma unroll
      for (int r = 0; r < 4; ++r) {
        const int row = m0 + wr * 64 + mi * 16 + g * 4 + r;
        const int col = n0 + wc * 64 + ni * 16 + lr;
        out[(size_t)row * 1024 + col] = acc[mi][ni][r] + bias[col];
      }
}

extern "C" void kernel_launch(void* const* d_in, const int* in_sizes, int n_in,
                              void* d_out, int out_size, void* d_ws, size_t ws_size,
                              hipStream_t stream) {
  (void)in_sizes; (void)n_in; (void)out_size; (void)ws_size;
  const float* x  = (const float*)d_in[0];
  const float* wq = (const float*)d_in[1];
  const float* wk = (const float*)d_in[2];
  const float* wv = (const float*)d_in[3];
  const float* wo = (const float*)d_in[4];
  const float* bo = (const float*)d_in[5];
  float* out = (float*)d_out;
  char* ws = (char*)d_ws;

  const size_t MB = 1024 * 1024;
  u16* xh   = (u16*)(ws + 0);        // 16 MB; reused as `multi` after qkv_gemm
  u16* xl   = (u16*)(ws + 16 * MB);  // 16 MB; reused as `vt` after qkv_gemm
  u16* qkh  = (u16*)(ws + 32 * MB);  // 32 MB
  u16* qkl  = (u16*)(ws + 64 * MB);  // 32 MB
  u16* vbf  = (u16*)(ws + 96 * MB);  // 16 MB
  u16* wqkh = (u16*)(ws + 112 * MB); // 4 MB
  u16* wqkl = (u16*)(ws + 116 * MB); // 4 MB
  u16* wvb  = (u16*)(ws + 120 * MB); // 2 MB
  u16* wob  = (u16*)(ws + 122 * MB); // 2 MB
  u16* multi = xh;                   // x dead after qkv_gemm
  u16* vt    = xl;                   // x dead after qkv_gemm

  prep_x<<<8192, 256, 0, stream>>>(x, xh, xl);
  prep_w<<<4096, 256, 0, stream>>>(wq, wk, wv, wo, wqkh, wqkl, wvb, wob);
  qkv_gemm<<<dim3(24, 64), 256, 0, stream>>>(xh, xl, wqkh, wqkl, wvb, qkh, qkl, vbf);
  vtrans<<<dim3(16, 128), 256, 0, stream>>>(vbf, vt);
  attn<<<512, 256, 0, stream>>>(qkh, qkl, vt, multi);
  out_gemm<<<dim3(8, 64), 256, 0, stream>>>(multi, wob, bo, out);
}

// Round 7
// 347.458 us; speedup vs baseline: 1.0599x; 1.0599x over previous
//
#include <hip/hip_runtime.h>
#include <hip/hip_bf16.h>
#include <stdint.h>

typedef unsigned short u16;
typedef short bf16x8 __attribute__((ext_vector_type(8)));
typedef float f32x4 __attribute__((ext_vector_type(4)));
typedef uint32_t u32x4 __attribute__((ext_vector_type(4)));

#define DEV __device__ __forceinline__

DEV u16 f2bf(float f) {            // RNE (exact, for hi/lo splits)
  union { float f; uint32_t u; } v; v.f = f;
  uint32_t u = v.u;
  return (u16)((u + 0x7FFFu + ((u >> 16) & 1u)) >> 16);
}
DEV float bf2f(u16 h) {
  union { uint32_t u; float f; } v; v.u = ((uint32_t)h) << 16;
  return v.f;
}
DEV uint32_t cvtpk_bf16(float lo, float hi) {   // dst[15:0]=bf(lo), dst[31:16]=bf(hi)
  uint32_t r;
  asm volatile("v_cvt_pk_bf16_f32 %0, %1, %2" : "=v"(r) : "v"(lo), "v"(hi));
  return r;
}

#if __has_builtin(__builtin_amdgcn_exp2f)
#define EXP2F(x) __builtin_amdgcn_exp2f(x)
#else
#define EXP2F(x) exp2f(x)
#endif

#define GLL(gp, lp) __builtin_amdgcn_global_load_lds(\
    (const __attribute__((address_space(1))) unsigned int*)(gp), \
    (__attribute__((address_space(3))) unsigned int*)(lp), 16, 0, 0)

// ---------------- prep kernels ----------------
__global__ void prep_x(const float* __restrict__ x, u16* __restrict__ xh, u16* __restrict__ xl) {
  int i = blockIdx.x * 256 + threadIdx.x;
  float4 v = ((const float4*)x)[i];
  ushort4 h, lo;
  h.x = f2bf(v.x); h.y = f2bf(v.y); h.z = f2bf(v.z); h.w = f2bf(v.w);
  lo.x = f2bf(v.x - bf2f(h.x)); lo.y = f2bf(v.y - bf2f(h.y));
  lo.z = f2bf(v.z - bf2f(h.z)); lo.w = f2bf(v.w - bf2f(h.w));
  ((ushort4*)xh)[i] = h;
  ((ushort4*)xl)[i] = lo;
}

__global__ void prep_w(const float* __restrict__ wq, const float* __restrict__ wk,
                       const float* __restrict__ wv, const float* __restrict__ wo,
                       u16* __restrict__ wqkh, u16* __restrict__ wqkl,
                       u16* __restrict__ wvb, u16* __restrict__ wob) {
  int i = blockIdx.x * 256 + threadIdx.x;
  int seg = i >> 18;
  int j = i & ((1 << 18) - 1);
  const float* src = (seg == 0) ? wq : (seg == 1) ? wk : (seg == 2) ? wv : wo;
  float4 v = ((const float4*)src)[j];
  ushort4 h;
  h.x = f2bf(v.x); h.y = f2bf(v.y); h.z = f2bf(v.z); h.w = f2bf(v.w);
  if (seg < 2) {
    ushort4 lo;
    lo.x = f2bf(v.x - bf2f(h.x)); lo.y = f2bf(v.y - bf2f(h.y));
    lo.z = f2bf(v.z - bf2f(h.z)); lo.w = f2bf(v.w - bf2f(h.w));
    ((ushort4*)wqkh)[i] = h;
    ((ushort4*)wqkl)[i] = lo;
  } else if (seg == 2) {
    ((ushort4*)wvb)[j] = h;
  } else {
    ((ushort4*)wob)[j] = h;
  }
}

// ---------------- fused QKV projection GEMM ----------------
__global__ __launch_bounds__(256, 2) void qkv_gemm(
    const u16* __restrict__ xh, const u16* __restrict__ xl,
    const u16* __restrict__ wh, const u16* __restrict__ wl,
    const u16* __restrict__ wv,
    u16* __restrict__ qkh, u16* __restrict__ qkl, u16* __restrict__ vout) {
  __shared__ u16 Ah[128 * 32], Al[128 * 32], Bh[128 * 32], Bl[128 * 32];
  const int t = threadIdx.x, w = t >> 6, l = t & 63, g = l >> 4, lr = l & 15;
  const int m0 = blockIdx.y * 128, n0 = blockIdx.x * 128;
  const bool split = (n0 < 2048);
  const u16* bsrc_h = split ? (wh + (size_t)n0 * 1024) : (wv + (size_t)(n0 - 2048) * 1024);
  const u16* bsrc_l = split ? (wl + (size_t)n0 * 1024) : wl;
  const int wr = w >> 1, wc = w & 1;

  f32x4 zero = {0.f, 0.f, 0.f, 0.f};
  f32x4 acc[4][4];
#pragma unroll
  for (int mi = 0; mi < 4; ++mi)
#pragma unroll
    for (int ni = 0; ni < 4; ++ni) acc[mi][ni] = zero;

  for (int k0 = 0; k0 < 1024; k0 += 32) {
    __syncthreads();
#pragma unroll
    for (int i = 0; i < 2; ++i) {
      const int c = i * 256 + t;
      const int row = c >> 2;
      const int kc8 = (c & 3) * 8;
      const size_t goff = (size_t)row * 1024 + k0 + kc8;
      const int lo = i * 4096 + w * 1024;
      GLL(xh + (size_t)m0 * 1024 + goff, (char*)Ah + lo);
      GLL(bsrc_h + goff, (char*)Bh + lo);
      if (split) {
        GLL(xl + (size_t)m0 * 1024 + goff, (char*)Al + lo);
        GLL(bsrc_l + goff, (char*)Bl + lo);
      }
    }
    __syncthreads();

    bf16x8 ah[4], al[4];
#pragma unroll
    for (int mi = 0; mi < 4; ++mi) {
      const int idx = (wr * 64 + mi * 16 + lr) * 32 + g * 8;
      ah[mi] = *(const bf16x8*)&Ah[idx];
      if (split) al[mi] = *(const bf16x8*)&Al[idx];
    }
#pragma unroll
    for (int ni = 0; ni < 4; ++ni) {
      const int idx = (wc * 64 + ni * 16 + lr) * 32 + g * 8;
      bf16x8 bh = *(const bf16x8*)&Bh[idx];
      bf16x8 bl;
      if (split) bl = *(const bf16x8*)&Bl[idx];
#pragma unroll
      for (int mi = 0; mi < 4; ++mi) {
        acc[mi][ni] = __builtin_amdgcn_mfma_f32_16x16x32_bf16(ah[mi], bh, acc[mi][ni], 0, 0, 0);
        if (split) {
          acc[mi][ni] = __builtin_amdgcn_mfma_f32_16x16x32_bf16(al[mi], bh, acc[mi][ni], 0, 0, 0);
          acc[mi][ni] = __builtin_amdgcn_mfma_f32_16x16x32_bf16(ah[mi], bl, acc[mi][ni], 0, 0, 0);
        }
      }
    }
  }

#pragma unroll
  for (int mi = 0; mi < 4; ++mi)
#pragma unroll
    for (int ni = 0; ni < 4; ++ni)
#pragma unroll
      for (int r = 0; r < 4; ++r) {
        const int row = m0 + wr * 64 + mi * 16 + g * 4 + r;
        const int col = wc * 64 + ni * 16 + lr;
        const float cval = acc[mi][ni][r];
        if (split) {
          const u16 h = f2bf(cval);
          qkh[(size_t)row * 2048 + n0 + col] = h;
          qkl[(size_t)row * 2048 + n0 + col] = f2bf(cval - bf2f(h));
        } else {
          vout[(size_t)row * 1024 + (n0 - 2048) + col] = f2bf(cval);
        }
      }
}

// ---------------- V transpose: vbf[8192][1024] -> vt[1024][8192] ----------------
__global__ __launch_bounds__(256) void vtrans(const u16* __restrict__ vin, u16* __restrict__ vout) {
  __shared__ u16 Ts[64 * 66];
  const int t = threadIdx.x;
  const int r0 = blockIdx.y * 64, c0 = blockIdx.x * 64;
  const int rl = t >> 3, cc = (t & 7) * 8;
#pragma unroll
  for (int i = 0; i < 2; ++i) {
    const int r = rl + i * 32;
    bf16x8 v = *(const bf16x8*)&vin[(size_t)(r0 + r) * 1024 + c0 + cc];
#pragma unroll
    for (int e = 0; e < 8; ++e) Ts[(cc + e) * 66 + r] = (u16)v[e];
  }
  __syncthreads();
  const int c = t >> 2, seg = (t & 3) * 16;
  u16 tmp[16];
#pragma unroll
  for (int e = 0; e < 16; ++e) tmp[e] = Ts[c * 66 + seg + e];
  *(bf16x8*)&vout[(size_t)(c0 + c) * 8192 + r0 + seg] = *(const bf16x8*)&tmp[0];
  *(bf16x8*)&vout[(size_t)(c0 + c) * 8192 + r0 + seg + 8] = *(const bf16x8*)&tmp[8];
}

// ---------------- flash attention with ALiBi (8 waves x 32q, 256 q/block) ----------------
// K rows staged PERMUTED: physical row p holds logical k = invp(p) with
// invp(p) = (p>>5)*32 + ((p>>2)&3)*8 + ((p>>4)&1)*4 + (p&3). After swapped
// QK^T, lane (g,lr) slot (mt,r) = logical k = (mt>>1)*32 + g*8 + (mt&1)*4 + r
// == exactly the PV B-fragment element this lane needs -> P assembled fully
// in-register (cvt_pk pairs), ZERO LDS for P, PV swapped to O^T = V^T x P^T.
// O^T cols = q = lr -> softmax state / rescale / 1/l all lane-local.
// LDS 48KB (K hi/lo + V dbuf only). Dbuf, 1 barrier/tile.
__global__ __launch_bounds__(512, 2) void attn(
    const u16* __restrict__ qkh, const u16* __restrict__ qkl,
    const u16* __restrict__ vt, u16* __restrict__ multi) {
  __shared__ u16 Ksh[2][4096], Ksl[2][4096], Vts[2][4096];
  const int t = threadIdx.x, w = t >> 6, l = t & 63, g = l >> 4, lr = l & 15;
  // XCD-chunked bijective swizzle
  const int L = blockIdx.x;
  const int flat = (L & 7) * 64 + (L >> 3);
  const int b = flat >> 7, h = (flat >> 3) & 15, qt = flat & 7;
  const int q0 = qt * 256;
  const size_t rowbase = (size_t)b * 2048;
  const u16* Qh = qkh + rowbase * 2048 + h * 64;
  const u16* Ql = qkl + rowbase * 2048 + h * 64;
  const u16* Kh = qkh + rowbase * 2048 + 1024 + h * 64;
  const u16* Kl = qkl + rowbase * 2048 + 1024 + h * 64;
  const u16* Vb = vt + (size_t)(h * 64) * 8192 + b * 2048;

  // staging: wave w stages physical rows w*8..w*8+7 of each 64x64 tile
  const int srow = l >> 3;
  const int sj = (l & 7) ^ srow;          // pre-swizzled source chunk (phys-row swizzle)
  const int krow = w * 8 + srow;          // physical row (K) / d-row (V)
  // logical K source row for permuted staging
  const int klog = ((krow >> 5) << 5) | (((krow >> 2) & 3) << 3)
                 | (((krow >> 4) & 1) << 2) | (krow & 3);
  const int ldsoff = w * 1024;            // bytes

  bf16x8 qfh[2][2], qfl[2][2];
#pragma unroll
  for (int nt = 0; nt < 2; ++nt)
#pragma unroll
    for (int kc = 0; kc < 2; ++kc) {
      const size_t off = (size_t)(q0 + w * 32 + nt * 16 + lr) * 2048 + kc * 32 + g * 8;
      qfh[nt][kc] = *(const bf16x8*)&Qh[off];
      qfl[nt][kc] = *(const bf16x8*)&Ql[off];
    }

  f32x4 zero = {0.f, 0.f, 0.f, 0.f};
  f32x4 o[2][4];                          // o[nt][dn]: O^T rows d=dn*16+g*4+r, col q=nt*16+lr
#pragma unroll
  for (int nt = 0; nt < 2; ++nt)
#pragma unroll
    for (int dn = 0; dn < 4; ++dn) o[nt][dn] = zero;
  float mst[2] = {-3.0e38f, -3.0e38f};   // per q = nt*16+lr (lane-local)
  float lst[2] = {0.f, 0.f};

  // exp2-domain; slot (mt,g,r) logical k = kt + (mt>>1)*32 + (mt&1)*4 + g*8 + r
  const float c1 = 0.125f * 1.44269504088896f;
  const float slope2 = -(float)(h + 1) * 1.44269504088896f;
  const float s2r1 = slope2, s2r2 = slope2 * 2.0f, s2r3 = slope2 * 3.0f;
  float base[4];
#pragma unroll
  for (int mt = 0; mt < 4; ++mt)
    base[mt] = slope2 * (float)(((mt >> 1) << 5) + ((mt & 1) << 2) + g * 8);
  const float bstep = slope2 * 64.0f;

  // prologue: stage tile 0 into buffer 0 (K rows permuted via klog)
  GLL(Kh + (size_t)klog * 2048 + sj * 8, (char*)&Ksh[0][0] + ldsoff);
  GLL(Kl + (size_t)klog * 2048 + sj * 8, (char*)&Ksl[0][0] + ldsoff);
  GLL(Vb + (size_t)krow * 8192 + sj * 8, (char*)&Vts[0][0] + ldsoff);
  __syncthreads();

  int cur = 0;
  for (int kt = 0; kt < 2048; kt += 64) {
    if (kt + 64 < 2048) {
      const int nxt = cur ^ 1;
      GLL(Kh + (size_t)(kt + 64 + klog) * 2048 + sj * 8, (char*)&Ksh[nxt][0] + ldsoff);
      GLL(Kl + (size_t)(kt + 64 + klog) * 2048 + sj * 8, (char*)&Ksl[nxt][0] + ldsoff);
      GLL(Vb + (size_t)krow * 8192 + kt + 64 + sj * 8, (char*)&Vts[nxt][0] + ldsoff);
    }
    const u16* Kcur = &Ksh[cur][0];
    const u16* Lcur = &Ksl[cur][0];
    const u16* Vcur = &Vts[cur][0];

    // S^T = K x Q^T (3-product split bf16): c[mt][nt], physical k rows
    f32x4 c[4][2];
#pragma unroll
    for (int mt = 0; mt < 4; ++mt)
#pragma unroll
      for (int nt = 0; nt < 2; ++nt) c[mt][nt] = zero;
    __builtin_amdgcn_s_setprio(1);
#pragma unroll
    for (int mt = 0; mt < 4; ++mt) {
      bf16x8 ah[2], al[2];
#pragma unroll
      for (int kc = 0; kc < 2; ++kc) {
        const int rk = mt * 16 + lr;
        const int byte = rk * 128 + (((kc * 4 + g) ^ (rk & 7)) << 4);
        ah[kc] = *(const bf16x8*)((const char*)Kcur + byte);
        al[kc] = *(const bf16x8*)((const char*)Lcur + byte);
      }
#pragma unroll
      for (int nt = 0; nt < 2; ++nt) {
        f32x4 a = c[mt][nt];
        a = __builtin_amdgcn_mfma_f32_16x16x32_bf16(ah[0], qfh[nt][0], a, 0, 0, 0);
        a = __builtin_amdgcn_mfma_f32_16x16x32_bf16(ah[1], qfh[nt][1], a, 0, 0, 0);
        a = __builtin_amdgcn_mfma_f32_16x16x32_bf16(al[0], qfh[nt][0], a, 0, 0, 0);
        a = __builtin_amdgcn_mfma_f32_16x16x32_bf16(al[1], qfh[nt][1], a, 0, 0, 0);
        a = __builtin_amdgcn_mfma_f32_16x16x32_bf16(ah[0], qfl[nt][0], a, 0, 0, 0);
        a = __builtin_amdgcn_mfma_f32_16x16x32_bf16(ah[1], qfl[nt][1], a, 0, 0, 0);
        c[mt][nt] = a;
      }
    }
    __builtin_amdgcn_s_setprio(0);

    // ALiBi (permutation-aware constants) + lane-local online softmax
#pragma unroll
    for (int mt = 0; mt < 4; ++mt)
#pragma unroll
      for (int nt = 0; nt < 2; ++nt) {
        f32x4 a = c[mt][nt];
        a[0] = fmaf(a[0], c1, base[mt]);
        a[1] = fmaf(a[1], c1, base[mt] + s2r1);
        a[2] = fmaf(a[2], c1, base[mt] + s2r2);
        a[3] = fmaf(a[3], c1, base[mt] + s2r3);
        c[mt][nt] = a;
      }
    float rmax[2];
#pragma unroll
    for (int nt = 0; nt < 2; ++nt) {
      float m01 = fmaxf(fmaxf(c[0][nt][0], c[0][nt][1]), fmaxf(c[0][nt][2], c[0][nt][3]));
      float m23 = fmaxf(fmaxf(c[1][nt][0], c[1][nt][1]), fmaxf(c[1][nt][2], c[1][nt][3]));
      float m45 = fmaxf(fmaxf(c[2][nt][0], c[2][nt][1]), fmaxf(c[2][nt][2], c[2][nt][3]));
      float m67 = fmaxf(fmaxf(c[3][nt][0], c[3][nt][1]), fmaxf(c[3][nt][2], c[3][nt][3]));
      float m = fmaxf(fmaxf(m01, m23), fmaxf(m45, m67));
      m = fmaxf(m, __shfl_xor(m, 16));
      m = fmaxf(m, __shfl_xor(m, 32));
      rmax[nt] = m;
    }
    const bool need = (rmax[0] > mst[0]) | (rmax[1] > mst[1]);
    if (__any(need)) {
#pragma unroll
      for (int nt = 0; nt < 2; ++nt) {
        const float mn = fmaxf(mst[nt], rmax[nt]);
        const float alpha = EXP2F(mst[nt] - mn);
        mst[nt] = mn;
        lst[nt] *= alpha;
#pragma unroll
        for (int dn = 0; dn < 4; ++dn) {
          o[nt][dn][0] *= alpha; o[nt][dn][1] *= alpha;
          o[nt][dn][2] *= alpha; o[nt][dn][3] *= alpha;
        }
      }
    }
    // exp + in-register P fragments (zero LDS, zero shuffle)
    bf16x8 pb[2][2];
#pragma unroll
    for (int nt = 0; nt < 2; ++nt) {
      float rsum = 0.f;
      uint32_t pk01[4], pk23[4];
#pragma unroll
      for (int mt = 0; mt < 4; ++mt) {
        const float p0 = EXP2F(c[mt][nt][0] - mst[nt]);
        const float p1 = EXP2F(c[mt][nt][1] - mst[nt]);
        const float p2 = EXP2F(c[mt][nt][2] - mst[nt]);
        const float p3 = EXP2F(c[mt][nt][3] - mst[nt]);
        rsum += (p0 + p1) + (p2 + p3);
        pk01[mt] = cvtpk_bf16(p0, p1);
        pk23[mt] = cvtpk_bf16(p2, p3);
      }
      rsum += __shfl_xor(rsum, 16);
      rsum += __shfl_xor(rsum, 32);
      lst[nt] += rsum;
      union { u32x4 u; bf16x8 bf; } cv0, cv1;
      cv0.u = (u32x4){pk01[0], pk23[0], pk01[1], pk23[1]};
      cv1.u = (u32x4){pk01[2], pk23[2], pk01[3], pk23[3]};
      pb[nt][0] = cv0.bf;
      pb[nt][1] = cv1.bf;
    }

    // PV swapped: O^T[d][q] = V^T x P^T
    __builtin_amdgcn_s_setprio(1);
#pragma unroll
    for (int dn = 0; dn < 4; ++dn) {
      bf16x8 vb[2];
#pragma unroll
      for (int kc = 0; kc < 2; ++kc) {
        const int row = dn * 16 + lr;
        const int jk = kc * 4 + g;
        const int byte = row * 128 + ((jk ^ (row & 7)) << 4);
        vb[kc] = *(const bf16x8*)((const char*)Vcur + byte);
      }
#pragma unroll
      for (int nt = 0; nt < 2; ++nt) {
        o[nt][dn] = __builtin_amdgcn_mfma_f32_16x16x32_bf16(vb[0], pb[nt][0], o[nt][dn], 0, 0, 0);
        o[nt][dn] = __builtin_amdgcn_mfma_f32_16x16x32_bf16(vb[1], pb[nt][1], o[nt][dn], 0, 0, 0);
      }
    }
    __builtin_amdgcn_s_setprio(0);

#pragma unroll
    for (int mt = 0; mt < 4; ++mt) base[mt] += bstep;

    __syncthreads();   // vmcnt(0) drain: next tile's stage has landed
    cur ^= 1;
  }

  // epilogue: lane-local 1/l, packed 8B stores (4 consecutive d per store)
#pragma unroll
  for (int nt = 0; nt < 2; ++nt) {
    const float rinv = 1.0f / lst[nt];
    const int qrow = q0 + w * 32 + nt * 16 + lr;
#pragma unroll
    for (int dn = 0; dn < 4; ++dn) {
      uint2 pkv;
      pkv.x = cvtpk_bf16(o[nt][dn][0] * rinv, o[nt][dn][1] * rinv);
      pkv.y = cvtpk_bf16(o[nt][dn][2] * rinv, o[nt][dn][3] * rinv);
      *(uint2*)&multi[(rowbase + qrow) * 1024 + h * 64 + dn * 16 + g * 4] = pkv;
    }
  }
}

// ---------------- output GEMM + bias ----------------
__global__ __launch_bounds__(256, 2) void out_gemm(
    const u16* __restrict__ A, const u16* __restrict__ Bw,
    const float* __restrict__ bias, float* __restrict__ out) {
  __shared__ u16 As[128 * 32], Bs[128 * 32];
  const int t = threadIdx.x, w = t >> 6, l = t & 63, g = l >> 4, lr = l & 15;
  const int m0 = blockIdx.y * 128, n0 = blockIdx.x * 128;
  const int wr = w >> 1, wc = w & 1;

  f32x4 zero = {0.f, 0.f, 0.f, 0.f};
  f32x4 acc[4][4];
#pragma unroll
  for (int mi = 0; mi < 4; ++mi)
#pragma unroll
    for (int ni = 0; ni < 4; ++ni) acc[mi][ni] = zero;

  for (int k0 = 0; k0 < 1024; k0 += 32) {
    __syncthreads();
#pragma unroll
    for (int i = 0; i < 2; ++i) {
      const int c = i * 256 + t;
      const int row = c >> 2;
      const int kc8 = (c & 3) * 8;
      const size_t goff = (size_t)row * 1024 + k0 + kc8;
      const int lo = i * 4096 + w * 1024;
      GLL(A + (size_t)m0 * 1024 + goff, (char*)As + lo);
      GLL(Bw + (size_t)n0 * 1024 + goff, (char*)Bs + lo);
    }
    __syncthreads();

    bf16x8 ah[4];
#pragma unroll
    for (int mi = 0; mi < 4; ++mi)
      ah[mi] = *(const bf16x8*)&As[(wr * 64 + mi * 16 + lr) * 32 + g * 8];
#pragma unroll
    for (int ni = 0; ni < 4; ++ni) {
      bf16x8 bh = *(const bf16x8*)&Bs[(wc * 64 + ni * 16 + lr) * 32 + g * 8];
#pragma unroll
      for (int mi = 0; mi < 4; ++mi)
        acc[mi][ni] = __builtin_amdgcn_mfma_f32_16x16x32_bf16(ah[mi], bh, acc[mi][ni], 0, 0, 0);
    }
  }

#pragma unroll
  for (int mi = 0; mi < 4; ++mi)
#pragma unroll
    for (int ni = 0; ni < 4; ++ni)
#pragma unroll
      for (int r = 0; r < 4; ++r) {
        const int row = m0 + wr * 64 + mi * 16 + g * 4 + r;
        const int col = n0 + wc * 64 + ni * 16 + lr;
        out[(size_t)row * 1024 + col] = acc[mi][ni][r] + bias[col];
      }
}

extern "C" void kernel_launch(void* const* d_in, const int* in_sizes, int n_in,
                              void* d_out, int out_size, void* d_ws, size_t ws_size,
                              hipStream_t stream) {
  (void)in_sizes; (void)n_in; (void)out_size; (void)ws_size;
  const float* x  = (const float*)d_in[0];
  const float* wq = (const float*)d_in[1];
  const float* wk = (const float*)d_in[2];
  const float* wv = (const float*)d_in[3];
  const float* wo = (const float*)d_in[4];
  const float* bo = (const float*)d_in[5];
  float* out = (float*)d_out;
  char* ws = (char*)d_ws;

  const size_t MB = 1024 * 1024;
  u16* xh   = (u16*)(ws + 0);        // 16 MB; reused as `multi` after qkv_gemm
  u16* xl   = (u16*)(ws + 16 * MB);  // 16 MB; reused as `vt` after qkv_gemm
  u16* qkh  = (u16*)(ws + 32 * MB);  // 32 MB
  u16* qkl  = (u16*)(ws + 64 * MB);  // 32 MB
  u16* vbf  = (u16*)(ws + 96 * MB);  // 16 MB
  u16* wqkh = (u16*)(ws + 112 * MB); // 4 MB
  u16* wqkl = (u16*)(ws + 116 * MB); // 4 MB
  u16* wvb  = (u16*)(ws + 120 * MB); // 2 MB
  u16* wob  = (u16*)(ws + 122 * MB); // 2 MB
  u16* multi = xh;                   // x dead after qkv_gemm
  u16* vt    = xl;                   // x dead after qkv_gemm

  prep_x<<<8192, 256, 0, stream>>>(x, xh, xl);
  prep_w<<<4096, 256, 0, stream>>>(wq, wk, wv, wo, wqkh, wqkl, wvb, wob);
  qkv_gemm<<<dim3(24, 64), 256, 0, stream>>>(xh, xl, wqkh, wqkl, wvb, qkh, qkl, vbf);
  vtrans<<<dim3(16, 128), 256, 0, stream>>>(vbf, vt);
  attn<<<512, 512, 0, stream>>>(qkh, qkl, vt, multi);
  out_gemm<<<dim3(8, 64), 256, 0, stream>>>(multi, wob, bo, out);
}

// Round 8
// 343.499 us; speedup vs baseline: 1.0721x; 1.0115x over previous
//
#include <hip/hip_runtime.h>
#include <hip/hip_bf16.h>
#include <stdint.h>

typedef unsigned short u16;
typedef short bf16x8 __attribute__((ext_vector_type(8)));
typedef float f32x4 __attribute__((ext_vector_type(4)));
typedef uint32_t u32x4 __attribute__((ext_vector_type(4)));

#define DEV __device__ __forceinline__

DEV u16 f2bf(float f) {            // RNE (exact, for hi/lo splits)
  union { float f; uint32_t u; } v; v.f = f;
  uint32_t u = v.u;
  return (u16)((u + 0x7FFFu + ((u >> 16) & 1u)) >> 16);
}
DEV float bf2f(u16 h) {
  union { uint32_t u; float f; } v; v.u = ((uint32_t)h) << 16;
  return v.f;
}
DEV uint32_t cvtpk_bf16(float lo, float hi) {   // dst[15:0]=bf(lo), dst[31:16]=bf(hi)
  uint32_t r;
  asm volatile("v_cvt_pk_bf16_f32 %0, %1, %2" : "=v"(r) : "v"(lo), "v"(hi));
  return r;
}

#if __has_builtin(__builtin_amdgcn_exp2f)
#define EXP2F(x) __builtin_amdgcn_exp2f(x)
#else
#define EXP2F(x) exp2f(x)
#endif

#define GLL(gp, lp) __builtin_amdgcn_global_load_lds(\
    (const __attribute__((address_space(1))) unsigned int*)(gp), \
    (__attribute__((address_space(3))) unsigned int*)(lp), 16, 0, 0)

// ---------------- prep kernels ----------------
__global__ void prep_x(const float* __restrict__ x, u16* __restrict__ xh, u16* __restrict__ xl) {
  int i = blockIdx.x * 256 + threadIdx.x;
  float4 v = ((const float4*)x)[i];
  ushort4 h, lo;
  h.x = f2bf(v.x); h.y = f2bf(v.y); h.z = f2bf(v.z); h.w = f2bf(v.w);
  lo.x = f2bf(v.x - bf2f(h.x)); lo.y = f2bf(v.y - bf2f(h.y));
  lo.z = f2bf(v.z - bf2f(h.z)); lo.w = f2bf(v.w - bf2f(h.w));
  ((ushort4*)xh)[i] = h;
  ((ushort4*)xl)[i] = lo;
}

__global__ void prep_w(const float* __restrict__ wq, const float* __restrict__ wk,
                       const float* __restrict__ wv, const float* __restrict__ wo,
                       u16* __restrict__ wqkh, u16* __restrict__ wqkl,
                       u16* __restrict__ wvb, u16* __restrict__ wob) {
  int i = blockIdx.x * 256 + threadIdx.x;
  int seg = i >> 18;
  int j = i & ((1 << 18) - 1);
  const float* src = (seg == 0) ? wq : (seg == 1) ? wk : (seg == 2) ? wv : wo;
  float4 v = ((const float4*)src)[j];
  ushort4 h;
  h.x = f2bf(v.x); h.y = f2bf(v.y); h.z = f2bf(v.z); h.w = f2bf(v.w);
  if (seg < 2) {
    ushort4 lo;
    lo.x = f2bf(v.x - bf2f(h.x)); lo.y = f2bf(v.y - bf2f(h.y));
    lo.z = f2bf(v.z - bf2f(h.z)); lo.w = f2bf(v.w - bf2f(h.w));
    ((ushort4*)wqkh)[i] = h;
    ((ushort4*)wqkl)[i] = lo;
  } else if (seg == 2) {
    ((ushort4*)wvb)[j] = h;
  } else {
    ((ushort4*)wob)[j] = h;
  }
}

// ---------------- fused QKV projection GEMM ----------------
__global__ __launch_bounds__(256, 2) void qkv_gemm(
    const u16* __restrict__ xh, const u16* __restrict__ xl,
    const u16* __restrict__ wh, const u16* __restrict__ wl,
    const u16* __restrict__ wv,
    u16* __restrict__ qkh, u16* __restrict__ qkl, u16* __restrict__ vout) {
  __shared__ u16 Ah[128 * 32], Al[128 * 32], Bh[128 * 32], Bl[128 * 32];
  const int t = threadIdx.x, w = t >> 6, l = t & 63, g = l >> 4, lr = l & 15;
  const int m0 = blockIdx.y * 128, n0 = blockIdx.x * 128;
  const bool split = (n0 < 2048);
  const u16* bsrc_h = split ? (wh + (size_t)n0 * 1024) : (wv + (size_t)(n0 - 2048) * 1024);
  const u16* bsrc_l = split ? (wl + (size_t)n0 * 1024) : wl;
  const int wr = w >> 1, wc = w & 1;

  f32x4 zero = {0.f, 0.f, 0.f, 0.f};
  f32x4 acc[4][4];
#pragma unroll
  for (int mi = 0; mi < 4; ++mi)
#pragma unroll
    for (int ni = 0; ni < 4; ++ni) acc[mi][ni] = zero;

  for (int k0 = 0; k0 < 1024; k0 += 32) {
    __syncthreads();
#pragma unroll
    for (int i = 0; i < 2; ++i) {
      const int c = i * 256 + t;
      const int row = c >> 2;
      const int kc8 = (c & 3) * 8;
      const size_t goff = (size_t)row * 1024 + k0 + kc8;
      const int lo = i * 4096 + w * 1024;
      GLL(xh + (size_t)m0 * 1024 + goff, (char*)Ah + lo);
      GLL(bsrc_h + goff, (char*)Bh + lo);
      if (split) {
        GLL(xl + (size_t)m0 * 1024 + goff, (char*)Al + lo);
        GLL(bsrc_l + goff, (char*)Bl + lo);
      }
    }
    __syncthreads();

    bf16x8 ah[4], al[4];
#pragma unroll
    for (int mi = 0; mi < 4; ++mi) {
      const int idx = (wr * 64 + mi * 16 + lr) * 32 + g * 8;
      ah[mi] = *(const bf16x8*)&Ah[idx];
      if (split) al[mi] = *(const bf16x8*)&Al[idx];
    }
#pragma unroll
    for (int ni = 0; ni < 4; ++ni) {
      const int idx = (wc * 64 + ni * 16 + lr) * 32 + g * 8;
      bf16x8 bh = *(const bf16x8*)&Bh[idx];
      bf16x8 bl;
      if (split) bl = *(const bf16x8*)&Bl[idx];
#pragma unroll
      for (int mi = 0; mi < 4; ++mi) {
        acc[mi][ni] = __builtin_amdgcn_mfma_f32_16x16x32_bf16(ah[mi], bh, acc[mi][ni], 0, 0, 0);
        if (split) {
          acc[mi][ni] = __builtin_amdgcn_mfma_f32_16x16x32_bf16(al[mi], bh, acc[mi][ni], 0, 0, 0);
          acc[mi][ni] = __builtin_amdgcn_mfma_f32_16x16x32_bf16(ah[mi], bl, acc[mi][ni], 0, 0, 0);
        }
      }
    }
  }

#pragma unroll
  for (int mi = 0; mi < 4; ++mi)
#pragma unroll
    for (int ni = 0; ni < 4; ++ni)
#pragma unroll
      for (int r = 0; r < 4; ++r) {
        const int row = m0 + wr * 64 + mi * 16 + g * 4 + r;
        const int col = wc * 64 + ni * 16 + lr;
        const float cval = acc[mi][ni][r];
        if (split) {
          const u16 h = f2bf(cval);
          qkh[(size_t)row * 2048 + n0 + col] = h;
          qkl[(size_t)row * 2048 + n0 + col] = f2bf(cval - bf2f(h));
        } else {
          vout[(size_t)row * 1024 + (n0 - 2048) + col] = f2bf(cval);
        }
      }
}

// ---------------- V transpose: vbf[8192][1024] -> vt[1024][8192] ----------------
__global__ __launch_bounds__(256) void vtrans(const u16* __restrict__ vin, u16* __restrict__ vout) {
  __shared__ u16 Ts[64 * 66];
  const int t = threadIdx.x;
  const int r0 = blockIdx.y * 64, c0 = blockIdx.x * 64;
  const int rl = t >> 3, cc = (t & 7) * 8;
#pragma unroll
  for (int i = 0; i < 2; ++i) {
    const int r = rl + i * 32;
    bf16x8 v = *(const bf16x8*)&vin[(size_t)(r0 + r) * 1024 + c0 + cc];
#pragma unroll
    for (int e = 0; e < 8; ++e) Ts[(cc + e) * 66 + r] = (u16)v[e];
  }
  __syncthreads();
  const int c = t >> 2, seg = (t & 3) * 16;
  u16 tmp[16];
#pragma unroll
  for (int e = 0; e < 16; ++e) tmp[e] = Ts[c * 66 + seg + e];
  *(bf16x8*)&vout[(size_t)(c0 + c) * 8192 + r0 + seg] = *(const bf16x8*)&tmp[0];
  *(bf16x8*)&vout[(size_t)(c0 + c) * 8192 + r0 + seg + 8] = *(const bf16x8*)&tmp[8];
}

// ---------------- flash attention with ALiBi (8 waves x 32q, 256 q/block) ----------------
// Round-7 structure (permuted K staging, zero-shuffle in-reg P, swapped PV,
// lane-local softmax) + 2-deep register pipeline: QK(t+1) -> cB overlaps
// softmax+PV(t) on cA (independent MFMA vs VALU streams interleave per-wave).
// Triple-buffered K/V LDS (72 KB, tile x -> buf x%3), 1 barrier/tile.
__global__ __launch_bounds__(512, 2) void attn(
    const u16* __restrict__ qkh, const u16* __restrict__ qkl,
    const u16* __restrict__ vt, u16* __restrict__ multi) {
  __shared__ u16 Ksh[3][4096], Ksl[3][4096], Vts[3][4096];
  const int t = threadIdx.x, w = t >> 6, l = t & 63, g = l >> 4, lr = l & 15;
  // XCD-chunked bijective swizzle
  const int L = blockIdx.x;
  const int flat = (L & 7) * 64 + (L >> 3);
  const int b = flat >> 7, h = (flat >> 3) & 15, qt = flat & 7;
  const int q0 = qt * 256;
  const size_t rowbase = (size_t)b * 2048;
  const u16* Qh = qkh + rowbase * 2048 + h * 64;
  const u16* Ql = qkl + rowbase * 2048 + h * 64;
  const u16* Kh = qkh + rowbase * 2048 + 1024 + h * 64;
  const u16* Kl = qkl + rowbase * 2048 + 1024 + h * 64;
  const u16* Vb = vt + (size_t)(h * 64) * 8192 + b * 2048;

  // staging: wave w stages physical rows w*8..w*8+7 of each 64x64 tile
  const int srow = l >> 3;
  const int sj = (l & 7) ^ srow;          // pre-swizzled source chunk
  const int krow = w * 8 + srow;          // physical row (K) / d-row (V)
  // logical K source row for permuted staging
  const int klog = ((krow >> 5) << 5) | (((krow >> 2) & 3) << 3)
                 | (((krow >> 4) & 1) << 2) | (krow & 3);
  const int ldsoff = w * 1024;            // bytes

  bf16x8 qfh[2][2], qfl[2][2];
#pragma unroll
  for (int nt = 0; nt < 2; ++nt)
#pragma unroll
    for (int kc = 0; kc < 2; ++kc) {
      const size_t off = (size_t)(q0 + w * 32 + nt * 16 + lr) * 2048 + kc * 32 + g * 8;
      qfh[nt][kc] = *(const bf16x8*)&Qh[off];
      qfl[nt][kc] = *(const bf16x8*)&Ql[off];
    }

  f32x4 zero = {0.f, 0.f, 0.f, 0.f};
  f32x4 o[2][4];                          // O^T rows d=dn*16+g*4+r, col q=nt*16+lr
#pragma unroll
  for (int nt = 0; nt < 2; ++nt)
#pragma unroll
    for (int dn = 0; dn < 4; ++dn) o[nt][dn] = zero;
  float mst[2] = {-3.0e38f, -3.0e38f};   // per q = nt*16+lr (lane-local)
  float lst[2] = {0.f, 0.f};

  // exp2-domain; slot (mt,g,r) logical k = kt + (mt>>1)*32 + (mt&1)*4 + g*8 + r
  const float c1 = 0.125f * 1.44269504088896f;
  const float slope2 = -(float)(h + 1) * 1.44269504088896f;
  const float s2r1 = slope2, s2r2 = slope2 * 2.0f, s2r3 = slope2 * 3.0f;
  float base[4];
#pragma unroll
  for (int mt = 0; mt < 4; ++mt)
    base[mt] = slope2 * (float)(((mt >> 1) << 5) + ((mt & 1) << 2) + g * 8);
  const float bstep = slope2 * 64.0f;

  auto STAGE = [&](int tile, int buf) {
    GLL(Kh + (size_t)(tile * 64 + klog) * 2048 + sj * 8, (char*)&Ksh[buf][0] + ldsoff);
    GLL(Kl + (size_t)(tile * 64 + klog) * 2048 + sj * 8, (char*)&Ksl[buf][0] + ldsoff);
    GLL(Vb + (size_t)krow * 8192 + tile * 64 + sj * 8, (char*)&Vts[buf][0] + ldsoff);
  };

  auto QK = [&](int buf, f32x4 (&c)[4][2]) {
    const u16* Kcur = &Ksh[buf][0];
    const u16* Lcur = &Ksl[buf][0];
#pragma unroll
    for (int mt = 0; mt < 4; ++mt)
#pragma unroll
      for (int nt = 0; nt < 2; ++nt) c[mt][nt] = zero;
    __builtin_amdgcn_s_setprio(1);
#pragma unroll
    for (int mt = 0; mt < 4; ++mt) {
      bf16x8 ah[2], al[2];
#pragma unroll
      for (int kc = 0; kc < 2; ++kc) {
        const int rk = mt * 16 + lr;
        const int byte = rk * 128 + (((kc * 4 + g) ^ (rk & 7)) << 4);
        ah[kc] = *(const bf16x8*)((const char*)Kcur + byte);
        al[kc] = *(const bf16x8*)((const char*)Lcur + byte);
      }
#pragma unroll
      for (int nt = 0; nt < 2; ++nt) {
        f32x4 a = c[mt][nt];
        a = __builtin_amdgcn_mfma_f32_16x16x32_bf16(ah[0], qfh[nt][0], a, 0, 0, 0);
        a = __builtin_amdgcn_mfma_f32_16x16x32_bf16(ah[1], qfh[nt][1], a, 0, 0, 0);
        a = __builtin_amdgcn_mfma_f32_16x16x32_bf16(al[0], qfh[nt][0], a, 0, 0, 0);
        a = __builtin_amdgcn_mfma_f32_16x16x32_bf16(al[1], qfh[nt][1], a, 0, 0, 0);
        a = __builtin_amdgcn_mfma_f32_16x16x32_bf16(ah[0], qfl[nt][0], a, 0, 0, 0);
        a = __builtin_amdgcn_mfma_f32_16x16x32_bf16(ah[1], qfl[nt][1], a, 0, 0, 0);
        c[mt][nt] = a;
      }
    }
    __builtin_amdgcn_s_setprio(0);
  };

  auto SMPV = [&](f32x4 (&c)[4][2], int buf) {
    const u16* Vcur = &Vts[buf][0];
    // ALiBi (permutation-aware constants)
#pragma unroll
    for (int mt = 0; mt < 4; ++mt)
#pragma unroll
      for (int nt = 0; nt < 2; ++nt) {
        f32x4 a = c[mt][nt];
        a[0] = fmaf(a[0], c1, base[mt]);
        a[1] = fmaf(a[1], c1, base[mt] + s2r1);
        a[2] = fmaf(a[2], c1, base[mt] + s2r2);
        a[3] = fmaf(a[3], c1, base[mt] + s2r3);
        c[mt][nt] = a;
      }
    float rmax[2];
#pragma unroll
    for (int nt = 0; nt < 2; ++nt) {
      float m01 = fmaxf(fmaxf(c[0][nt][0], c[0][nt][1]), fmaxf(c[0][nt][2], c[0][nt][3]));
      float m23 = fmaxf(fmaxf(c[1][nt][0], c[1][nt][1]), fmaxf(c[1][nt][2], c[1][nt][3]));
      float m45 = fmaxf(fmaxf(c[2][nt][0], c[2][nt][1]), fmaxf(c[2][nt][2], c[2][nt][3]));
      float m67 = fmaxf(fmaxf(c[3][nt][0], c[3][nt][1]), fmaxf(c[3][nt][2], c[3][nt][3]));
      float m = fmaxf(fmaxf(m01, m23), fmaxf(m45, m67));
      m = fmaxf(m, __shfl_xor(m, 16));
      m = fmaxf(m, __shfl_xor(m, 32));
      rmax[nt] = m;
    }
    const bool needr = (rmax[0] > mst[0]) | (rmax[1] > mst[1]);
    if (__any(needr)) {
#pragma unroll
      for (int nt = 0; nt < 2; ++nt) {
        const float mn = fmaxf(mst[nt], rmax[nt]);
        const float alpha = EXP2F(mst[nt] - mn);
        mst[nt] = mn;
        lst[nt] *= alpha;
#pragma unroll
        for (int dn = 0; dn < 4; ++dn) {
          o[nt][dn][0] *= alpha; o[nt][dn][1] *= alpha;
          o[nt][dn][2] *= alpha; o[nt][dn][3] *= alpha;
        }
      }
    }
    // exp + in-register P fragments (zero LDS, zero shuffle)
    bf16x8 pb[2][2];
#pragma unroll
    for (int nt = 0; nt < 2; ++nt) {
      float rsum = 0.f;
      uint32_t pk01[4], pk23[4];
#pragma unroll
      for (int mt = 0; mt < 4; ++mt) {
        const float p0 = EXP2F(c[mt][nt][0] - mst[nt]);
        const float p1 = EXP2F(c[mt][nt][1] - mst[nt]);
        const float p2 = EXP2F(c[mt][nt][2] - mst[nt]);
        const float p3 = EXP2F(c[mt][nt][3] - mst[nt]);
        rsum += (p0 + p1) + (p2 + p3);
        pk01[mt] = cvtpk_bf16(p0, p1);
        pk23[mt] = cvtpk_bf16(p2, p3);
      }
      rsum += __shfl_xor(rsum, 16);
      rsum += __shfl_xor(rsum, 32);
      lst[nt] += rsum;
      union { u32x4 u; bf16x8 bf; } cv0, cv1;
      cv0.u = (u32x4){pk01[0], pk23[0], pk01[1], pk23[1]};
      cv1.u = (u32x4){pk01[2], pk23[2], pk01[3], pk23[3]};
      pb[nt][0] = cv0.bf;
      pb[nt][1] = cv1.bf;
    }
    // PV swapped: O^T[d][q] = V^T x P^T
    __builtin_amdgcn_s_setprio(1);
#pragma unroll
    for (int dn = 0; dn < 4; ++dn) {
      bf16x8 vb[2];
#pragma unroll
      for (int kc = 0; kc < 2; ++kc) {
        const int row = dn * 16 + lr;
        const int jk = kc * 4 + g;
        const int byte = row * 128 + ((jk ^ (row & 7)) << 4);
        vb[kc] = *(const bf16x8*)((const char*)Vcur + byte);
      }
#pragma unroll
      for (int nt = 0; nt < 2; ++nt) {
        o[nt][dn] = __builtin_amdgcn_mfma_f32_16x16x32_bf16(vb[0], pb[nt][0], o[nt][dn], 0, 0, 0);
        o[nt][dn] = __builtin_amdgcn_mfma_f32_16x16x32_bf16(vb[1], pb[nt][1], o[nt][dn], 0, 0, 0);
      }
    }
    __builtin_amdgcn_s_setprio(0);
#pragma unroll
    for (int mt = 0; mt < 4; ++mt) base[mt] += bstep;
  };

  // prologue: stage tiles 0,1; first QK
  STAGE(0, 0);
  STAGE(1, 1);
  __syncthreads();             // tiles 0,1 ready
  f32x4 cA[4][2], cB[4][2];
  QK(0, cA);

  // main: 15 iters, 2 tiles each; finish t & t+1, QK runs one tile ahead
  for (int kt = 0; kt < 30; kt += 2) {
    STAGE(kt + 2, (kt + 2) % 3);   // overwrites buf of tile kt-1 (readers done pre-barrier)
    QK((kt + 1) % 3, cB);          // MFMA stream, independent of cA softmax
    SMPV(cA, kt % 3);              // VALU softmax + PV on tile kt
    __syncthreads();               // drains stage(kt+2)
    STAGE(kt + 3, (kt + 3) % 3);
    QK((kt + 2) % 3, cA);
    SMPV(cB, (kt + 1) % 3);
    __syncthreads();
  }
  // tail: cA = QK(30); tile 31 staged in buf 1
  QK(31 % 3, cB);
  SMPV(cA, 30 % 3);
  SMPV(cB, 31 % 3);

  // epilogue: lane-local 1/l, packed 8B stores
#pragma unroll
  for (int nt = 0; nt < 2; ++nt) {
    const float rinv = 1.0f / lst[nt];
    const int qrow = q0 + w * 32 + nt * 16 + lr;
#pragma unroll
    for (int dn = 0; dn < 4; ++dn) {
      uint2 pkv;
      pkv.x = cvtpk_bf16(o[nt][dn][0] * rinv, o[nt][dn][1] * rinv);
      pkv.y = cvtpk_bf16(o[nt][dn][2] * rinv, o[nt][dn][3] * rinv);
      *(uint2*)&multi[(rowbase + qrow) * 1024 + h * 64 + dn * 16 + g * 4] = pkv;
    }
  }
}

// ---------------- output GEMM + bias ----------------
__global__ __launch_bounds__(256, 2) void out_gemm(
    const u16* __restrict__ A, const u16* __restrict__ Bw,
    const float* __restrict__ bias, float* __restrict__ out) {
  __shared__ u16 As[128 * 32], Bs[128 * 32];
  const int t = threadIdx.x, w = t >> 6, l = t & 63, g = l >> 4, lr = l & 15;
  const int m0 = blockIdx.y * 128, n0 = blockIdx.x * 128;
  const int wr = w >> 1, wc = w & 1;

  f32x4 zero = {0.f, 0.f, 0.f, 0.f};
  f32x4 acc[4][4];
#pragma unroll
  for (int mi = 0; mi < 4; ++mi)
#pragma unroll
    for (int ni = 0; ni < 4; ++ni) acc[mi][ni] = zero;

  for (int k0 = 0; k0 < 1024; k0 += 32) {
    __syncthreads();
#pragma unroll
    for (int i = 0; i < 2; ++i) {
      const int c = i * 256 + t;
      const int row = c >> 2;
      const int kc8 = (c & 3) * 8;
      const size_t goff = (size_t)row * 1024 + k0 + kc8;
      const int lo = i * 4096 + w * 1024;
      GLL(A + (size_t)m0 * 1024 + goff, (char*)As + lo);
      GLL(Bw + (size_t)n0 * 1024 + goff, (char*)Bs + lo);
    }
    __syncthreads();

    bf16x8 ah[4];
#pragma unroll
    for (int mi = 0; mi < 4; ++mi)
      ah[mi] = *(const bf16x8*)&As[(wr * 64 + mi * 16 + lr) * 32 + g * 8];
#pragma unroll
    for (int ni = 0; ni < 4; ++ni) {
      bf16x8 bh = *(const bf16x8*)&Bs[(wc * 64 + ni * 16 + lr) * 32 + g * 8];
#pragma unroll
      for (int mi = 0; mi < 4; ++mi)
        acc[mi][ni] = __builtin_amdgcn_mfma_f32_16x16x32_bf16(ah[mi], bh, acc[mi][ni], 0, 0, 0);
    }
  }

#pragma unroll
  for (int mi = 0; mi < 4; ++mi)
#pragma unroll
    for (int ni = 0; ni < 4; ++ni)
#pragma unroll
      for (int r = 0; r < 4; ++r) {
        const int row = m0 + wr * 64 + mi * 16 + g * 4 + r;
        const int col = n0 + wc * 64 + ni * 16 + lr;
        out[(size_t)row * 1024 + col] = acc[mi][ni][r] + bias[col];
      }
}

extern "C" void kernel_launch(void* const* d_in, const int* in_sizes, int n_in,
                              void* d_out, int out_size, void* d_ws, size_t ws_size,
                              hipStream_t stream) {
  (void)in_sizes; (void)n_in; (void)out_size; (void)ws_size;
  const float* x  = (const float*)d_in[0];
  const float* wq = (const float*)d_in[1];
  const float* wk = (const float*)d_in[2];
  const float* wv = (const float*)d_in[3];
  const float* wo = (const float*)d_in[4];
  const float* bo = (const float*)d_in[5];
  float* out = (float*)d_out;
  char* ws = (char*)d_ws;

  const size_t MB = 1024 * 1024;
  u16* xh   = (u16*)(ws + 0);        // 16 MB; reused as `multi` after qkv_gemm
  u16* xl   = (u16*)(ws + 16 * MB);  // 16 MB; reused as `vt` after qkv_gemm
  u16* qkh  = (u16*)(ws + 32 * MB);  // 32 MB
  u16* qkl  = (u16*)(ws + 64 * MB);  // 32 MB
  u16* vbf  = (u16*)(ws + 96 * MB);  // 16 MB
  u16* wqkh = (u16*)(ws + 112 * MB); // 4 MB
  u16* wqkl = (u16*)(ws + 116 * MB); // 4 MB
  u16* wvb  = (u16*)(ws + 120 * MB); // 2 MB
  u16* wob  = (u16*)(ws + 122 * MB); // 2 MB
  u16* multi = xh;                   // x dead after qkv_gemm
  u16* vt    = xl;                   // x dead after qkv_gemm

  prep_x<<<8192, 256, 0, stream>>>(x, xh, xl);
  prep_w<<<4096, 256, 0, stream>>>(wq, wk, wv, wo, wqkh, wqkl, wvb, wob);
  qkv_gemm<<<dim3(24, 64), 256, 0, stream>>>(xh, xl, wqkh, wqkl, wvb, qkh, qkl, vbf);
  vtrans<<<dim3(16, 128), 256, 0, stream>>>(vbf, vt);
  attn<<<512, 512, 0, stream>>>(qkh, qkl, vt, multi);
  out_gemm<<<dim3(8, 64), 256, 0, stream>>>(multi, wob, bo, out);
}

// Round 9
// 340.893 us; speedup vs baseline: 1.0803x; 1.0076x over previous
//
#include <hip/hip_runtime.h>
#include <hip/hip_bf16.h>
#include <stdint.h>

typedef unsigned short u16;
typedef short bf16x8 __attribute__((ext_vector_type(8)));
typedef float f32x4 __attribute__((ext_vector_type(4)));
typedef uint32_t u32x4 __attribute__((ext_vector_type(4)));

#define DEV __device__ __forceinline__

DEV u16 f2bf(float f) {            // RNE (exact, for hi/lo splits)
  union { float f; uint32_t u; } v; v.f = f;
  uint32_t u = v.u;
  return (u16)((u + 0x7FFFu + ((u >> 16) & 1u)) >> 16);
}
DEV float bf2f(u16 h) {
  union { uint32_t u; float f; } v; v.u = ((uint32_t)h) << 16;
  return v.f;
}
DEV uint32_t cvtpk_bf16(float lo, float hi) {   // dst[15:0]=bf(lo), dst[31:16]=bf(hi)
  uint32_t r;
  asm volatile("v_cvt_pk_bf16_f32 %0, %1, %2" : "=v"(r) : "v"(lo), "v"(hi));
  return r;
}

#if __has_builtin(__builtin_amdgcn_exp2f)
#define EXP2F(x) __builtin_amdgcn_exp2f(x)
#else
#define EXP2F(x) exp2f(x)
#endif

#define GLL(gp, lp) __builtin_amdgcn_global_load_lds(\
    (const __attribute__((address_space(1))) unsigned int*)(gp), \
    (__attribute__((address_space(3))) unsigned int*)(lp), 16, 0, 0)

// ---------------- prep kernels ----------------
__global__ void prep_x(const float* __restrict__ x, u16* __restrict__ xh, u16* __restrict__ xl) {
  int i = blockIdx.x * 256 + threadIdx.x;
  float4 v = ((const float4*)x)[i];
  ushort4 h, lo;
  h.x = f2bf(v.x); h.y = f2bf(v.y); h.z = f2bf(v.z); h.w = f2bf(v.w);
  lo.x = f2bf(v.x - bf2f(h.x)); lo.y = f2bf(v.y - bf2f(h.y));
  lo.z = f2bf(v.z - bf2f(h.z)); lo.w = f2bf(v.w - bf2f(h.w));
  ((ushort4*)xh)[i] = h;
  ((ushort4*)xl)[i] = lo;
}

__global__ void prep_w(const float* __restrict__ wq, const float* __restrict__ wk,
                       const float* __restrict__ wv, const float* __restrict__ wo,
                       u16* __restrict__ wqkh, u16* __restrict__ wqkl,
                       u16* __restrict__ wvb, u16* __restrict__ wob) {
  int i = blockIdx.x * 256 + threadIdx.x;
  int seg = i >> 18;
  int j = i & ((1 << 18) - 1);
  const float* src = (seg == 0) ? wq : (seg == 1) ? wk : (seg == 2) ? wv : wo;
  float4 v = ((const float4*)src)[j];
  ushort4 h;
  h.x = f2bf(v.x); h.y = f2bf(v.y); h.z = f2bf(v.z); h.w = f2bf(v.w);
  if (seg < 2) {
    ushort4 lo;
    lo.x = f2bf(v.x - bf2f(h.x)); lo.y = f2bf(v.y - bf2f(h.y));
    lo.z = f2bf(v.z - bf2f(h.z)); lo.w = f2bf(v.w - bf2f(h.w));
    ((ushort4*)wqkh)[i] = h;
    ((ushort4*)wqkl)[i] = lo;
  } else if (seg == 2) {
    ((ushort4*)wvb)[j] = h;
  } else {
    ((ushort4*)wob)[j] = h;
  }
}

// ---------------- fused QKV projection GEMM ----------------
__global__ __launch_bounds__(256, 2) void qkv_gemm(
    const u16* __restrict__ xh, const u16* __restrict__ xl,
    const u16* __restrict__ wh, const u16* __restrict__ wl,
    const u16* __restrict__ wv,
    u16* __restrict__ qkh, u16* __restrict__ qkl, u16* __restrict__ vout) {
  __shared__ u16 Ah[128 * 32], Al[128 * 32], Bh[128 * 32], Bl[128 * 32];
  const int t = threadIdx.x, w = t >> 6, l = t & 63, g = l >> 4, lr = l & 15;
  const int m0 = blockIdx.y * 128, n0 = blockIdx.x * 128;
  const bool split = (n0 < 2048);
  const u16* bsrc_h = split ? (wh + (size_t)n0 * 1024) : (wv + (size_t)(n0 - 2048) * 1024);
  const u16* bsrc_l = split ? (wl + (size_t)n0 * 1024) : wl;
  const int wr = w >> 1, wc = w & 1;

  f32x4 zero = {0.f, 0.f, 0.f, 0.f};
  f32x4 acc[4][4];
#pragma unroll
  for (int mi = 0; mi < 4; ++mi)
#pragma unroll
    for (int ni = 0; ni < 4; ++ni) acc[mi][ni] = zero;

  for (int k0 = 0; k0 < 1024; k0 += 32) {
    __syncthreads();
#pragma unroll
    for (int i = 0; i < 2; ++i) {
      const int c = i * 256 + t;
      const int row = c >> 2;
      const int kc8 = (c & 3) * 8;
      const size_t goff = (size_t)row * 1024 + k0 + kc8;
      const int lo = i * 4096 + w * 1024;
      GLL(xh + (size_t)m0 * 1024 + goff, (char*)Ah + lo);
      GLL(bsrc_h + goff, (char*)Bh + lo);
      if (split) {
        GLL(xl + (size_t)m0 * 1024 + goff, (char*)Al + lo);
        GLL(bsrc_l + goff, (char*)Bl + lo);
      }
    }
    __syncthreads();

    bf16x8 ah[4], al[4];
#pragma unroll
    for (int mi = 0; mi < 4; ++mi) {
      const int idx = (wr * 64 + mi * 16 + lr) * 32 + g * 8;
      ah[mi] = *(const bf16x8*)&Ah[idx];
      if (split) al[mi] = *(const bf16x8*)&Al[idx];
    }
#pragma unroll
    for (int ni = 0; ni < 4; ++ni) {
      const int idx = (wc * 64 + ni * 16 + lr) * 32 + g * 8;
      bf16x8 bh = *(const bf16x8*)&Bh[idx];
      bf16x8 bl;
      if (split) bl = *(const bf16x8*)&Bl[idx];
#pragma unroll
      for (int mi = 0; mi < 4; ++mi) {
        acc[mi][ni] = __builtin_amdgcn_mfma_f32_16x16x32_bf16(ah[mi], bh, acc[mi][ni], 0, 0, 0);
        if (split) {
          acc[mi][ni] = __builtin_amdgcn_mfma_f32_16x16x32_bf16(al[mi], bh, acc[mi][ni], 0, 0, 0);
          acc[mi][ni] = __builtin_amdgcn_mfma_f32_16x16x32_bf16(ah[mi], bl, acc[mi][ni], 0, 0, 0);
        }
      }
    }
  }

#pragma unroll
  for (int mi = 0; mi < 4; ++mi)
#pragma unroll
    for (int ni = 0; ni < 4; ++ni)
#pragma unroll
      for (int r = 0; r < 4; ++r) {
        const int row = m0 + wr * 64 + mi * 16 + g * 4 + r;
        const int col = wc * 64 + ni * 16 + lr;
        const float cval = acc[mi][ni][r];
        if (split) {
          const u16 h = f2bf(cval);
          qkh[(size_t)row * 2048 + n0 + col] = h;
          qkl[(size_t)row * 2048 + n0 + col] = f2bf(cval - bf2f(h));
        } else {
          vout[(size_t)row * 1024 + (n0 - 2048) + col] = f2bf(cval);
        }
      }
}

// ---------------- V transpose: vbf[8192][1024] -> vt[1024][8192] ----------------
__global__ __launch_bounds__(256) void vtrans(const u16* __restrict__ vin, u16* __restrict__ vout) {
  __shared__ u16 Ts[64 * 66];
  const int t = threadIdx.x;
  const int r0 = blockIdx.y * 64, c0 = blockIdx.x * 64;
  const int rl = t >> 3, cc = (t & 7) * 8;
#pragma unroll
  for (int i = 0; i < 2; ++i) {
    const int r = rl + i * 32;
    bf16x8 v = *(const bf16x8*)&vin[(size_t)(r0 + r) * 1024 + c0 + cc];
#pragma unroll
    for (int e = 0; e < 8; ++e) Ts[(cc + e) * 66 + r] = (u16)v[e];
  }
  __syncthreads();
  const int c = t >> 2, seg = (t & 3) * 16;
  u16 tmp[16];
#pragma unroll
  for (int e = 0; e < 16; ++e) tmp[e] = Ts[c * 66 + seg + e];
  *(bf16x8*)&vout[(size_t)(c0 + c) * 8192 + r0 + seg] = *(const bf16x8*)&tmp[0];
  *(bf16x8*)&vout[(size_t)(c0 + c) * 8192 + r0 + seg + 8] = *(const bf16x8*)&tmp[8];
}

// ---------------- flash attention with ALiBi (8 waves x 32q, 256 q/block) ----------------
// Round-7 structure (permuted K staging, zero-shuffle in-reg P, swapped PV,
// lane-local softmax) + WAVE-GROUP PHASE STAGGER: group A (w<4) runs
// QK(t)->SMPV(t); group B (w>=4) runs SMPV(t-1)->QK(t). With wid%4 SIMD
// mapping every SIMD hosts one MFMA-phase and one VALU-phase wave per window
// -> MFMA and VALU pipes overlap instead of running in lockstep phases.
// Triple-buffered K/V LDS, stage 1 ahead: live tiles {t-1,t,t+1} mod-3 distinct.
__global__ __launch_bounds__(512, 2) void attn(
    const u16* __restrict__ qkh, const u16* __restrict__ qkl,
    const u16* __restrict__ vt, u16* __restrict__ multi) {
  __shared__ u16 Ksh[3][4096], Ksl[3][4096], Vts[3][4096];
  const int t = threadIdx.x, w = t >> 6, l = t & 63, g = l >> 4, lr = l & 15;
  // XCD-chunked bijective swizzle
  const int L = blockIdx.x;
  const int flat = (L & 7) * 64 + (L >> 3);
  const int b = flat >> 7, h = (flat >> 3) & 15, qt = flat & 7;
  const int q0 = qt * 256;
  const size_t rowbase = (size_t)b * 2048;
  const u16* Qh = qkh + rowbase * 2048 + h * 64;
  const u16* Ql = qkl + rowbase * 2048 + h * 64;
  const u16* Kh = qkh + rowbase * 2048 + 1024 + h * 64;
  const u16* Kl = qkl + rowbase * 2048 + 1024 + h * 64;
  const u16* Vb = vt + (size_t)(h * 64) * 8192 + b * 2048;

  // staging: wave w stages physical rows w*8..w*8+7 of each 64x64 tile
  const int srow = l >> 3;
  const int sj = (l & 7) ^ srow;          // pre-swizzled source chunk
  const int krow = w * 8 + srow;          // physical row (K) / d-row (V)
  // logical K source row for permuted staging
  const int klog = ((krow >> 5) << 5) | (((krow >> 2) & 3) << 3)
                 | (((krow >> 4) & 1) << 2) | (krow & 3);
  const int ldsoff = w * 1024;            // bytes

  bf16x8 qfh[2][2], qfl[2][2];
#pragma unroll
  for (int nt = 0; nt < 2; ++nt)
#pragma unroll
    for (int kc = 0; kc < 2; ++kc) {
      const size_t off = (size_t)(q0 + w * 32 + nt * 16 + lr) * 2048 + kc * 32 + g * 8;
      qfh[nt][kc] = *(const bf16x8*)&Qh[off];
      qfl[nt][kc] = *(const bf16x8*)&Ql[off];
    }

  f32x4 zero = {0.f, 0.f, 0.f, 0.f};
  f32x4 o[2][4];                          // O^T rows d=dn*16+g*4+r, col q=nt*16+lr
#pragma unroll
  for (int nt = 0; nt < 2; ++nt)
#pragma unroll
    for (int dn = 0; dn < 4; ++dn) o[nt][dn] = zero;
  float mst[2] = {-3.0e38f, -3.0e38f};   // per q = nt*16+lr (lane-local)
  float lst[2] = {0.f, 0.f};

  // exp2-domain; slot (mt,g,r) logical k = kt + (mt>>1)*32 + (mt&1)*4 + g*8 + r
  const float c1 = 0.125f * 1.44269504088896f;
  const float slope2 = -(float)(h + 1) * 1.44269504088896f;
  const float s2r1 = slope2, s2r2 = slope2 * 2.0f, s2r3 = slope2 * 3.0f;
  float base[4];
#pragma unroll
  for (int mt = 0; mt < 4; ++mt)
    base[mt] = slope2 * (float)(((mt >> 1) << 5) + ((mt & 1) << 2) + g * 8);
  const float bstep = slope2 * 64.0f;

  auto STAGE = [&](int tile, int buf) {
    GLL(Kh + (size_t)(tile * 64 + klog) * 2048 + sj * 8, (char*)&Ksh[buf][0] + ldsoff);
    GLL(Kl + (size_t)(tile * 64 + klog) * 2048 + sj * 8, (char*)&Ksl[buf][0] + ldsoff);
    GLL(Vb + (size_t)krow * 8192 + tile * 64 + sj * 8, (char*)&Vts[buf][0] + ldsoff);
  };

  auto QK = [&](int buf, f32x4 (&c)[4][2]) {
    const u16* Kcur = &Ksh[buf][0];
    const u16* Lcur = &Ksl[buf][0];
#pragma unroll
    for (int mt = 0; mt < 4; ++mt)
#pragma unroll
      for (int nt = 0; nt < 2; ++nt) c[mt][nt] = zero;
    __builtin_amdgcn_s_setprio(1);
#pragma unroll
    for (int mt = 0; mt < 4; ++mt) {
      bf16x8 ah[2], al[2];
#pragma unroll
      for (int kc = 0; kc < 2; ++kc) {
        const int rk = mt * 16 + lr;
        const int byte = rk * 128 + (((kc * 4 + g) ^ (rk & 7)) << 4);
        ah[kc] = *(const bf16x8*)((const char*)Kcur + byte);
        al[kc] = *(const bf16x8*)((const char*)Lcur + byte);
      }
#pragma unroll
      for (int nt = 0; nt < 2; ++nt) {
        f32x4 a = c[mt][nt];
        a = __builtin_amdgcn_mfma_f32_16x16x32_bf16(ah[0], qfh[nt][0], a, 0, 0, 0);
        a = __builtin_amdgcn_mfma_f32_16x16x32_bf16(ah[1], qfh[nt][1], a, 0, 0, 0);
        a = __builtin_amdgcn_mfma_f32_16x16x32_bf16(al[0], qfh[nt][0], a, 0, 0, 0);
        a = __builtin_amdgcn_mfma_f32_16x16x32_bf16(al[1], qfh[nt][1], a, 0, 0, 0);
        a = __builtin_amdgcn_mfma_f32_16x16x32_bf16(ah[0], qfl[nt][0], a, 0, 0, 0);
        a = __builtin_amdgcn_mfma_f32_16x16x32_bf16(ah[1], qfl[nt][1], a, 0, 0, 0);
        c[mt][nt] = a;
      }
    }
    __builtin_amdgcn_s_setprio(0);
  };

  auto SMPV = [&](f32x4 (&c)[4][2], int buf) {
    const u16* Vcur = &Vts[buf][0];
    // ALiBi (permutation-aware constants)
#pragma unroll
    for (int mt = 0; mt < 4; ++mt)
#pragma unroll
      for (int nt = 0; nt < 2; ++nt) {
        f32x4 a = c[mt][nt];
        a[0] = fmaf(a[0], c1, base[mt]);
        a[1] = fmaf(a[1], c1, base[mt] + s2r1);
        a[2] = fmaf(a[2], c1, base[mt] + s2r2);
        a[3] = fmaf(a[3], c1, base[mt] + s2r3);
        c[mt][nt] = a;
      }
    float rmax[2];
#pragma unroll
    for (int nt = 0; nt < 2; ++nt) {
      float m01 = fmaxf(fmaxf(c[0][nt][0], c[0][nt][1]), fmaxf(c[0][nt][2], c[0][nt][3]));
      float m23 = fmaxf(fmaxf(c[1][nt][0], c[1][nt][1]), fmaxf(c[1][nt][2], c[1][nt][3]));
      float m45 = fmaxf(fmaxf(c[2][nt][0], c[2][nt][1]), fmaxf(c[2][nt][2], c[2][nt][3]));
      float m67 = fmaxf(fmaxf(c[3][nt][0], c[3][nt][1]), fmaxf(c[3][nt][2], c[3][nt][3]));
      float m = fmaxf(fmaxf(m01, m23), fmaxf(m45, m67));
      m = fmaxf(m, __shfl_xor(m, 16));
      m = fmaxf(m, __shfl_xor(m, 32));
      rmax[nt] = m;
    }
    const bool needr = (rmax[0] > mst[0]) | (rmax[1] > mst[1]);
    if (__any(needr)) {
#pragma unroll
      for (int nt = 0; nt < 2; ++nt) {
        const float mn = fmaxf(mst[nt], rmax[nt]);
        const float alpha = EXP2F(mst[nt] - mn);
        mst[nt] = mn;
        lst[nt] *= alpha;
#pragma unroll
        for (int dn = 0; dn < 4; ++dn) {
          o[nt][dn][0] *= alpha; o[nt][dn][1] *= alpha;
          o[nt][dn][2] *= alpha; o[nt][dn][3] *= alpha;
        }
      }
    }
    // exp + in-register P fragments (zero LDS, zero shuffle)
    bf16x8 pb[2][2];
#pragma unroll
    for (int nt = 0; nt < 2; ++nt) {
      float rsum = 0.f;
      uint32_t pk01[4], pk23[4];
#pragma unroll
      for (int mt = 0; mt < 4; ++mt) {
        const float p0 = EXP2F(c[mt][nt][0] - mst[nt]);
        const float p1 = EXP2F(c[mt][nt][1] - mst[nt]);
        const float p2 = EXP2F(c[mt][nt][2] - mst[nt]);
        const float p3 = EXP2F(c[mt][nt][3] - mst[nt]);
        rsum += (p0 + p1) + (p2 + p3);
        pk01[mt] = cvtpk_bf16(p0, p1);
        pk23[mt] = cvtpk_bf16(p2, p3);
      }
      rsum += __shfl_xor(rsum, 16);
      rsum += __shfl_xor(rsum, 32);
      lst[nt] += rsum;
      union { u32x4 u; bf16x8 bf; } cv0, cv1;
      cv0.u = (u32x4){pk01[0], pk23[0], pk01[1], pk23[1]};
      cv1.u = (u32x4){pk01[2], pk23[2], pk01[3], pk23[3]};
      pb[nt][0] = cv0.bf;
      pb[nt][1] = cv1.bf;
    }
    // PV swapped: O^T[d][q] = V^T x P^T
    __builtin_amdgcn_s_setprio(1);
#pragma unroll
    for (int dn = 0; dn < 4; ++dn) {
      bf16x8 vb[2];
#pragma unroll
      for (int kc = 0; kc < 2; ++kc) {
        const int row = dn * 16 + lr;
        const int jk = kc * 4 + g;
        const int byte = row * 128 + ((jk ^ (row & 7)) << 4);
        vb[kc] = *(const bf16x8*)((const char*)Vcur + byte);
      }
#pragma unroll
      for (int nt = 0; nt < 2; ++nt) {
        o[nt][dn] = __builtin_amdgcn_mfma_f32_16x16x32_bf16(vb[0], pb[nt][0], o[nt][dn], 0, 0, 0);
        o[nt][dn] = __builtin_amdgcn_mfma_f32_16x16x32_bf16(vb[1], pb[nt][1], o[nt][dn], 0, 0, 0);
      }
    }
    __builtin_amdgcn_s_setprio(0);
#pragma unroll
    for (int mt = 0; mt < 4; ++mt) base[mt] += bstep;
  };

  // prologue: stage tile 0
  STAGE(0, 0);
  __syncthreads();

  f32x4 cR[4][2];   // score state (group A: within-window; group B: spans one window)

  for (int kt = 0; kt < 32; ++kt) {
    if (kt + 1 < 32) STAGE(kt + 1, (kt + 1) % 3);
    if (w < 4) {
      QK(kt % 3, cR);            // MFMA first
      SMPV(cR, kt % 3);          // then VALU+PV
    } else {
      if (kt > 0) SMPV(cR, (kt + 2) % 3);  // VALU first (tile kt-1)
      QK(kt % 3, cR);                      // then MFMA (tile kt)
    }
    __syncthreads();             // drains STAGE(kt+1)
  }
  if (w >= 4) SMPV(cR, 31 % 3);  // group B finishes tile 31

  // epilogue: lane-local 1/l, packed 8B stores
#pragma unroll
  for (int nt = 0; nt < 2; ++nt) {
    const float rinv = 1.0f / lst[nt];
    const int qrow = q0 + w * 32 + nt * 16 + lr;
#pragma unroll
    for (int dn = 0; dn < 4; ++dn) {
      uint2 pkv;
      pkv.x = cvtpk_bf16(o[nt][dn][0] * rinv, o[nt][dn][1] * rinv);
      pkv.y = cvtpk_bf16(o[nt][dn][2] * rinv, o[nt][dn][3] * rinv);
      *(uint2*)&multi[(rowbase + qrow) * 1024 + h * 64 + dn * 16 + g * 4] = pkv;
    }
  }
}

// ---------------- output GEMM + bias ----------------
__global__ __launch_bounds__(256, 2) void out_gemm(
    const u16* __restrict__ A, const u16* __restrict__ Bw,
    const float* __restrict__ bias, float* __restrict__ out) {
  __shared__ u16 As[128 * 32], Bs[128 * 32];
  const int t = threadIdx.x, w = t >> 6, l = t & 63, g = l >> 4, lr = l & 15;
  const int m0 = blockIdx.y * 128, n0 = blockIdx.x * 128;
  const int wr = w >> 1, wc = w & 1;

  f32x4 zero = {0.f, 0.f, 0.f, 0.f};
  f32x4 acc[4][4];
#pragma unroll
  for (int mi = 0; mi < 4; ++mi)
#pragma unroll
    for (int ni = 0; ni < 4; ++ni) acc[mi][ni] = zero;

  for (int k0 = 0; k0 < 1024; k0 += 32) {
    __syncthreads();
#pragma unroll
    for (int i = 0; i < 2; ++i) {
      const int c = i * 256 + t;
      const int row = c >> 2;
      const int kc8 = (c & 3) * 8;
      const size_t goff = (size_t)row * 1024 + k0 + kc8;
      const int lo = i * 4096 + w * 1024;
      GLL(A + (size_t)m0 * 1024 + goff, (char*)As + lo);
      GLL(Bw + (size_t)n0 * 1024 + goff, (char*)Bs + lo);
    }
    __syncthreads();

    bf16x8 ah[4];
#pragma unroll
    for (int mi = 0; mi < 4; ++mi)
      ah[mi] = *(const bf16x8*)&As[(wr * 64 + mi * 16 + lr) * 32 + g * 8];
#pragma unroll
    for (int ni = 0; ni < 4; ++ni) {
      bf16x8 bh = *(const bf16x8*)&Bs[(wc * 64 + ni * 16 + lr) * 32 + g * 8];
#pragma unroll
      for (int mi = 0; mi < 4; ++mi)
        acc[mi][ni] = __builtin_amdgcn_mfma_f32_16x16x32_bf16(ah[mi], bh, acc[mi][ni], 0, 0, 0);
    }
  }

#pragma unroll
  for (int mi = 0; mi < 4; ++mi)
#pragma unroll
    for (int ni = 0; ni < 4; ++ni)
#pragma unroll
      for (int r = 0; r < 4; ++r) {
        const int row = m0 + wr * 64 + mi * 16 + g * 4 + r;
        const int col = n0 + wc * 64 + ni * 16 + lr;
        out[(size_t)row * 1024 + col] = acc[mi][ni][r] + bias[col];
      }
}

extern "C" void kernel_launch(void* const* d_in, const int* in_sizes, int n_in,
                              void* d_out, int out_size, void* d_ws, size_t ws_size,
                              hipStream_t stream) {
  (void)in_sizes; (void)n_in; (void)out_size; (void)ws_size;
  const float* x  = (const float*)d_in[0];
  const float* wq = (const float*)d_in[1];
  const float* wk = (const float*)d_in[2];
  const float* wv = (const float*)d_in[3];
  const float* wo = (const float*)d_in[4];
  const float* bo = (const float*)d_in[5];
  float* out = (float*)d_out;
  char* ws = (char*)d_ws;

  const size_t MB = 1024 * 1024;
  u16* xh   = (u16*)(ws + 0);        // 16 MB; reused as `multi` after qkv_gemm
  u16* xl   = (u16*)(ws + 16 * MB);  // 16 MB; reused as `vt` after qkv_gemm
  u16* qkh  = (u16*)(ws + 32 * MB);  // 32 MB
  u16* qkl  = (u16*)(ws + 64 * MB);  // 32 MB
  u16* vbf  = (u16*)(ws + 96 * MB);  // 16 MB
  u16* wqkh = (u16*)(ws + 112 * MB); // 4 MB
  u16* wqkl = (u16*)(ws + 116 * MB); // 4 MB
  u16* wvb  = (u16*)(ws + 120 * MB); // 2 MB
  u16* wob  = (u16*)(ws + 122 * MB); // 2 MB
  u16* multi = xh;                   // x dead after qkv_gemm
  u16* vt    = xl;                   // x dead after qkv_gemm

  prep_x<<<8192, 256, 0, stream>>>(x, xh, xl);
  prep_w<<<4096, 256, 0, stream>>>(wq, wk, wv, wo, wqkh, wqkl, wvb, wob);
  qkv_gemm<<<dim3(24, 64), 256, 0, stream>>>(xh, xl, wqkh, wqkl, wvb, qkh, qkl, vbf);
  vtrans<<<dim3(16, 128), 256, 0, stream>>>(vbf, vt);
  attn<<<512, 512, 0, stream>>>(qkh, qkl, vt, multi);
  out_gemm<<<dim3(8, 64), 256, 0, stream>>>(multi, wob, bo, out);
}